// Round 7
// baseline (267.981 us; speedup 1.0000x reference)
//
#include <hip/hip_runtime.h>

#define NUM_HEADS 16
#define HEAD_DIM  64
#define HIDDEN    1024
#define SEQ       512
#define BATCH     8
#define NBH       128      // BATCH*NUM_HEADS
#define POSN      512      // 2*BUCKET
#define SCALE_F   0.07216878364870323f   // 1/sqrt(3*HEAD_DIM)

typedef __attribute__((ext_vector_type(8))) short  short8;
typedef __attribute__((ext_vector_type(4))) short  short4_t;
typedef __attribute__((ext_vector_type(4))) float  floatx4;

// async global->LDS, 16B per lane (wave-uniform base + lane*16 dest)
#define GLDS16(gsrc, ldst) \
    __builtin_amdgcn_global_load_lds((const __attribute__((address_space(1))) void*)(gsrc), \
                                     (__attribute__((address_space(3))) void*)(ldst), 16, 0, 0)

__device__ __forceinline__ float bits2f(short s) {
    union { unsigned u; float f; } x;
    x.u = ((unsigned)(unsigned short)s) << 16;
    return x.f;
}
__device__ __forceinline__ short f2bits(float f) {
    union { float f; unsigned u; } x;
    x.f = f;
    unsigned r = x.u + 0x7fffu + ((x.u >> 16) & 1u);
    return (short)(r >> 16);
}

// ---------------------------------------------------------------------------
// prep: fp32 -> bf16 conversion for inputs and rel_embeddings
// ---------------------------------------------------------------------------
__global__ void conv_pair(const float* __restrict__ a, const float* __restrict__ b,
                          short* __restrict__ oa, short* __restrict__ ob)
{
    const int idx = blockIdx.x * 256 + threadIdx.x;    // one float4 each
    floatx4 va = ((const floatx4*)a)[idx];
    floatx4 vb = ((const floatx4*)b)[idx];
    short4_t ra, rb;
#pragma unroll
    for (int i = 0; i < 4; i++) { ra[i] = f2bits(va[i]); rb[i] = f2bits(vb[i]); }
    ((short4_t*)oa)[idx] = ra;
    ((short4_t*)ob)[idx] = rb;
}

// ---------------------------------------------------------------------------
// prep: transpose + convert the 4 weight matrices [1024][1024] -> bf16 [n][c]
// ---------------------------------------------------------------------------
__global__ void wtrans(const float* __restrict__ w0, const float* __restrict__ w1,
                       const float* __restrict__ w2, const float* __restrict__ w3,
                       short* __restrict__ o0, short* __restrict__ o1,
                       short* __restrict__ o2, short* __restrict__ o3)
{
    __shared__ float tile[64][65];
    const int z = blockIdx.z;
    const float* src = (z == 0) ? w0 : (z == 1) ? w1 : (z == 2) ? w2 : w3;
    short*       dst = (z == 0) ? o0 : (z == 1) ? o1 : (z == 2) ? o2 : o3;
    const int c0 = blockIdx.x * 64, n0 = blockIdx.y * 64;
    const int t = threadIdx.x;
#pragma unroll
    for (int j = 0; j < 16; j++) {
        const int e = t + j * 256;
        tile[e >> 6][e & 63] = src[(long)(c0 + (e >> 6)) * 1024 + n0 + (e & 63)];
    }
    __syncthreads();
#pragma unroll
    for (int j = 0; j < 16; j++) {
        const int e = t + j * 256;
        dst[(long)(n0 + (e >> 6)) * 1024 + c0 + (e & 63)] = f2bits(tile[e & 63][e >> 6]);
    }
}

// ---------------------------------------------------------------------------
// prep: 1-D log-bucket table  ftab[delta+511] = clip(bucket(delta)+256, 0, 511)
// ---------------------------------------------------------------------------
__global__ void ftab_build(int* __restrict__ ftab)
{
    const int i = blockIdx.x * 256 + threadIdx.x;
    if (i >= 1023) return;
    const int delta = i - 511;
    const float Cf = (float)log(511.0 / 128.0);
    float absp = (delta < 128 && delta > -128) ? 127.0f : fabsf((float)delta);
    float bucket;
    if (absp <= 128.0f) {
        bucket = (float)delta;
    } else {
        float lp = ceilf((logf(absp * (1.0f / 128.0f)) * 127.0f) / Cf) + 128.0f;
        bucket = (delta > 0) ? lp : -lp;
    }
    int bi = (int)bucket + 256;
    bi = min(max(bi, 0), 511);
    ftab[i] = bi;
}

// ---------------------------------------------------------------------------
// Generic NT GEMM: C[m,n] = sum_k A[m,k] * BT[n,k]   (bf16 in, fp32 acc)
// tile 128x128, BK=64, 256 threads (4 waves, 2x2), 16x16x32 bf16 MFMA
// Staging via global_load_lds width=16: linear LDS dest, inverse-swizzled
// global source chunk (cc = pc ^ (row&7)); swizzled LDS reads unchanged.
// MODE 1: plain -> bf16 out row-major [m*ldo+n], batched by z (O0)
// MODE 2: final -> fp32 out row-major + bias b0 (O0)
// MODE 4: QKV   -> n<1024: Q [b,h,s,d]+b0 (O0); n<2048: K +b1 (O1);
//                  else:   V [b,h,d,s]+b2 (O2)
// MODE 5: posQK -> n<1024: posQ [b,h,p,d]+b0 (O0); else posK +b1 (O1)
// ---------------------------------------------------------------------------
template<int MODE>
__global__ __launch_bounds__(256)
void gemm_nt(const short* __restrict__ A, long aBatch, int lda,
             const short* __restrict__ BT, long bBatch, int ldb,
             void* __restrict__ O0, void* __restrict__ O1, void* __restrict__ O2,
             long oBatch, int ldo,
             const float* __restrict__ b0, const float* __restrict__ b1,
             const float* __restrict__ b2, int Kd)
{
    __shared__ __align__(16) short As[128 * 64];
    __shared__ __align__(16) short Bs[128 * 64];
    const int z = blockIdx.z;
    const short* Ab = A + (long)z * aBatch;
    const short* Bb = BT + (long)z * bBatch;
    const int m0 = blockIdx.x * 128, n0 = blockIdx.y * 128;
    const int t = threadIdx.x;
    const int l = t & 63, w = t >> 6;
    const int wm = w >> 1, wn = w & 1;
    const int lr = l & 15, lg = l >> 4;

    floatx4 acc[4][4];
#pragma unroll
    for (int i = 0; i < 4; i++)
#pragma unroll
        for (int j = 0; j < 4; j++) acc[i][j] = (floatx4){0.f, 0.f, 0.f, 0.f};

    for (int k0 = 0; k0 < Kd; k0 += 64) {
        __syncthreads();
        // async staging: 1024 16B chunks per matrix; wave w owns chunks
        // [w*256, w*256+256); LDS linear, global source inverse-swizzled
#pragma unroll
        for (int j = 0; j < 4; j++) {
            const int c = (w * 4 + j) * 64 + l;   // 0..1023
            const int row = c >> 3, pc = c & 7;
            const int cc = pc ^ (row & 7);
            GLDS16(Ab + (long)(m0 + row) * lda + k0 + cc * 8, As + c * 8);
            GLDS16(Bb + (long)(n0 + row) * ldb + k0 + cc * 8, Bs + c * 8);
        }
        __syncthreads();
#pragma unroll
        for (int ks = 0; ks < 2; ks++) {
            short8 af[4], bfr[4];
#pragma unroll
            for (int i = 0; i < 4; i++) {
                const int mr = wm * 64 + i * 16 + lr;
                af[i] = *(const short8*)((char*)As + mr * 128 + (((ks * 4 + lg) ^ (mr & 7)) * 16));
                const int nr = wn * 64 + i * 16 + lr;
                bfr[i] = *(const short8*)((char*)Bs + nr * 128 + (((ks * 4 + lg) ^ (nr & 7)) * 16));
            }
#pragma unroll
            for (int i = 0; i < 4; i++)
#pragma unroll
                for (int j = 0; j < 4; j++)
                    acc[i][j] = __builtin_amdgcn_mfma_f32_16x16x32_bf16(af[i], bfr[j], acc[i][j], 0, 0, 0);
        }
    }

#pragma unroll
    for (int i = 0; i < 4; i++) {
#pragma unroll
        for (int j = 0; j < 4; j++) {
#pragma unroll
            for (int e = 0; e < 4; e++) {
                const int mg = m0 + wm * 64 + i * 16 + lg * 4 + e;
                const int ng = n0 + wn * 64 + j * 16 + lr;
                float v = acc[i][j][e];
                if (MODE == 1) {
                    ((short*)O0)[(long)z * oBatch + (long)mg * ldo + ng] = f2bits(v);
                } else if (MODE == 2) {
                    ((float*)O0)[(long)mg * ldo + ng] = v + b0[ng];
                } else if (MODE == 4) {
                    const int mat = ng >> 10, hh = ng & 1023, h = hh >> 6, d = hh & 63;
                    const int b = mg >> 9, s = mg & 511;
                    v += (mat == 0 ? b0 : mat == 1 ? b1 : b2)[hh];
                    short* dst = (short*)(mat == 0 ? O0 : mat == 1 ? O1 : O2);
                    if (mat == 2)
                        dst[((long)(b * NUM_HEADS + h) * HEAD_DIM + d) * SEQ + s] = f2bits(v);
                    else
                        dst[((long)(b * NUM_HEADS + h) * SEQ + s) * HEAD_DIM + d] = f2bits(v);
                } else {  // MODE 5
                    const int mat = ng >> 10, hh = ng & 1023, h = hh >> 6, d = hh & 63;
                    const int b = mg >> 9, s = mg & 511;
                    v += (mat == 0 ? b0 : b1)[hh];
                    short* dst = (short*)(mat == 0 ? O0 : O1);
                    dst[((long)(b * NUM_HEADS + h) * SEQ + s) * HEAD_DIM + d] = f2bits(v);
                }
            }
        }
    }
}

// ---------------------------------------------------------------------------
// relgather: IN-PLACE relayout  buf[bh][q][k] := buf[bh][f(q-k)][k]
// (bit-exact bf16 copy). Block = (k-stripe of 32, bh). Stage the whole
// 512x32 stripe in LDS first (read-set == write-set -> in-place safe);
// vector short8 writes.
// ---------------------------------------------------------------------------
__global__ __launch_bounds__(256, 4)
void relgather(short* __restrict__ buf, const int* __restrict__ ftab)
{
    __shared__ __align__(16) short pcs[512 * 32];   // 32 KB
    __shared__ short ft[1024];
    const int k0 = blockIdx.x * 32;
    const int bh = blockIdx.y;
    const int t = threadIdx.x;
    for (int i = t; i < 1024; i += 256) ft[i] = (short)((i < 1023) ? ftab[i] : 0);
    short* base = buf + (long)bh * SEQ * POSN;
    // stage: 512 rows x 64B (4 chunks of 16B) = 2048 chunks
#pragma unroll
    for (int j = 0; j < 8; j++) {
        const int chunk = t + j * 256;
        const int row = chunk >> 2, cc = chunk & 3;
        short8 v = *(const short8*)(base + (long)row * POSN + k0 + cc * 8);
        *(short8*)(pcs + row * 32 + cc * 8) = v;
    }
    __syncthreads();
    // write: 512 q-rows x 4 chunks of 8 = 2048 tasks, vector stores
#pragma unroll
    for (int j = 0; j < 8; j++) {
        const int task = t + j * 256;
        const int q = task >> 2, kc = task & 3;
        short8 v;
#pragma unroll
        for (int i = 0; i < 8; i++) {
            const int k = k0 + kc * 8 + i;
            const int fk = (int)ft[q - k + 511];
            v[i] = pcs[fk * 32 + kc * 8 + i];
        }
        *(short8*)(base + (long)q * POSN + k0 + kc * 8) = v;
    }
}

// ---------------------------------------------------------------------------
// Fused attention per (b,h, 16-row q-tile). 4 waves, 3 barriers.
//   c2p is COMPUTED in-kernel: c2pTile = Q-tile @ posK^T via MFMA (same shape
//   as QK^T; bit-identical rounding to the old GEMM path), written to LDS
//   (element XOR (r&7)<<3) and gathered. p2c' staged via global_load_lds.
//   softmax: shfl within 16-lane groups + tiny LDS cross-wave combine.
//   PV: wave w owns OUTPUT dims d in [w*16, w*16+16) -> no cross-wave reduce.
//   P-tile aliases the c2p LDS buffer (barrier-separated).
// LDS ~34.5 KB -> 4 blocks/CU.
// ---------------------------------------------------------------------------
__global__ __launch_bounds__(256, 4)
void attn_fused(const short* __restrict__ Q, const short* __restrict__ K,
                const short* __restrict__ Vt, const short* __restrict__ posK,
                const short* __restrict__ Gp2c, const int* __restrict__ ftab,
                short* __restrict__ attnO)
{
    __shared__ __align__(16) short c2pS[16 * 512];  // computed c2p; later P tile
    __shared__ __align__(16) short p2cS[16 * 512];  // p2c' rows (linear [q][k])
    __shared__ float red[2][4][16];
    __shared__ short ft[1024];

    // XCD-chunked swizzle: blocks of one bh land on one XCD (4096 % 8 == 0)
    const int lin  = blockIdx.x;
    const int lin2 = (lin & 7) * 512 + (lin >> 3);
    const int bh = lin2 >> 5, qt = lin2 & 31;
    const int q0 = qt * 16;
    const int t = threadIdx.x, l = t & 63, w = t >> 6;
    const int lr = l & 15, lg = l >> 4;
    const long pbase = (long)bh * SEQ * HEAD_DIM;
    const short* Qb  = Q  + pbase;
    const short* Kb  = K  + pbase;
    const short* Vtb = Vt + pbase;
    const short* pKb = posK + pbase;                 // [p][d], same layout as K
    const short* Gb  = Gp2c + (long)bh * SEQ * SEQ;

    for (int i = t; i < 1024; i += 256) ft[i] = (short)((i < 1023) ? ftab[i] : 0);

    // ---- stage p2c' rows async: 1024 chunks of 16B, wave w owns [w*256,+256) ----
#pragma unroll
    for (int j = 0; j < 4; j++) {
        const int c = (w * 4 + j) * 64 + l;   // 0..1023
        const int row = c >> 6, cc = c & 63;
        GLDS16(Gb + (long)(q0 + row) * SEQ + cc * 8, p2cS + c * 8);
    }

    // ---- Q fragments ----
    short8 aq[2];
#pragma unroll
    for (int ks = 0; ks < 2; ks++)
        aq[ks] = *(const short8*)(Qb + (q0 + lr) * 64 + ks * 32 + lg * 8);

    floatx4 acc[8];
#pragma unroll
    for (int nt = 0; nt < 8; nt++) acc[nt] = (floatx4){0.f, 0.f, 0.f, 0.f};

    // ---- QK^T + c2p MFMA (both operands straight from global/L2) ----
#pragma unroll
    for (int nt = 0; nt < 8; nt++) {
        const int kr = w * 128 + nt * 16 + lr;
        short8 kb0 = *(const short8*)(Kb + kr * 64 + lg * 8);
        short8 kb1 = *(const short8*)(Kb + kr * 64 + 32 + lg * 8);
        acc[nt] = __builtin_amdgcn_mfma_f32_16x16x32_bf16(aq[0], kb0, acc[nt], 0, 0, 0);
        acc[nt] = __builtin_amdgcn_mfma_f32_16x16x32_bf16(aq[1], kb1, acc[nt], 0, 0, 0);
        short8 pb0 = *(const short8*)(pKb + kr * 64 + lg * 8);
        short8 pb1 = *(const short8*)(pKb + kr * 64 + 32 + lg * 8);
        floatx4 accC = (floatx4){0.f, 0.f, 0.f, 0.f};
        accC = __builtin_amdgcn_mfma_f32_16x16x32_bf16(aq[0], pb0, accC, 0, 0, 0);
        accC = __builtin_amdgcn_mfma_f32_16x16x32_bf16(aq[1], pb1, accC, 0, 0, 0);
        // write c2p tile (row = local q, col = p = kr), element-XOR swizzle
#pragma unroll
        for (int e = 0; e < 4; e++) {
            const int row = lg * 4 + e;
            c2pS[row * 512 + (kr ^ ((row & 7) << 3))] = f2bits(accC[e]);
        }
    }
    __syncthreads();   // p2cS staged (vmcnt drained) + c2pS writes visible

    // ---- add c2p (LDS gather) + p2c (LDS linear), scale ----
#pragma unroll
    for (int nt = 0; nt < 8; nt++) {
        const int k = w * 128 + nt * 16 + lr;
#pragma unroll
        for (int e = 0; e < 4; e++) {
            const int r = lg * 4 + e;
            const int fk = (int)ft[q0 + r - k + 511];
            acc[nt][e] = (acc[nt][e] + bits2f(c2pS[r * 512 + (fk ^ ((r & 7) << 3))])
                                     + bits2f(p2cS[r * 512 + k])) * SCALE_F;
        }
    }

    // ---- wave-local row max -> LDS ----
#pragma unroll
    for (int e = 0; e < 4; e++) {
        float m = acc[0][e];
#pragma unroll
        for (int nt = 1; nt < 8; nt++) m = fmaxf(m, acc[nt][e]);
        m = fmaxf(m, __shfl_xor(m, 1));
        m = fmaxf(m, __shfl_xor(m, 2));
        m = fmaxf(m, __shfl_xor(m, 4));
        m = fmaxf(m, __shfl_xor(m, 8));
        red[0][w][lg * 4 + e] = m;
    }
    __syncthreads();   // also separates last c2pS gather-read from P-tile writes

    // ---- combine max, exp, sum, write P tile (aliases c2pS) ----
#pragma unroll
    for (int e = 0; e < 4; e++) {
        const int r = lg * 4 + e;
        const float m = fmaxf(fmaxf(red[0][0][r], red[0][1][r]),
                              fmaxf(red[0][2][r], red[0][3][r]));
        float s = 0.f;
#pragma unroll
        for (int nt = 0; nt < 8; nt++) {
            float p = __expf(acc[nt][e] - m);
            acc[nt][e] = p;
            s += p;
        }
        s += __shfl_xor(s, 1); s += __shfl_xor(s, 2);
        s += __shfl_xor(s, 4); s += __shfl_xor(s, 8);
        red[1][w][r] = s;
#pragma unroll
        for (int nt = 0; nt < 8; nt++) {
            const int kcol = w * 128 + nt * 16 + lr;
            int byte = r * 1024 + kcol * 2;
            byte ^= (r & 7) << 4;
            *(short*)((char*)c2pS + byte) = f2bits(acc[nt][e]);
        }
    }
    __syncthreads();

    // ---- PV: wave w owns d in [w*16, w*16+16), k-loop over all 512 ----
    floatx4 accO = (floatx4){0.f, 0.f, 0.f, 0.f};
#pragma unroll
    for (int ks = 0; ks < 16; ks++) {
        const int qr = lr;                       // A-frag row = q
        int byte = qr * 1024 + (ks * 32 + lg * 8) * 2;
        byte ^= (qr & 7) << 4;
        short8 pa = *(const short8*)((char*)c2pS + byte);
        short8 vb = *(const short8*)(Vtb + (long)(w * 16 + lr) * SEQ + ks * 32 + lg * 8);
        accO = __builtin_amdgcn_mfma_f32_16x16x32_bf16(pa, vb, accO, 0, 0, 0);
    }

    // ---- normalize + write ----
    const int b = bh >> 4, h = bh & 15;
#pragma unroll
    for (int e = 0; e < 4; e++) {
        const int r = lg * 4 + e;
        const float rs = red[1][0][r] + red[1][1][r] + red[1][2][r] + red[1][3][r];
        const float v = accO[e] / rs;
        attnO[((long)(b * SEQ + q0 + r)) * HIDDEN + h * HEAD_DIM + w * 16 + lr] = f2bits(v);
    }
}

// ---------------------------------------------------------------------------
extern "C" void kernel_launch(void* const* d_in, const int* in_sizes, int n_in,
                              void* d_out, int out_size, void* d_ws, size_t ws_size,
                              hipStream_t stream)
{
    const float* inputs = (const float*)d_in[0];
    const float* rel    = (const float*)d_in[1];
    const float* Wq     = (const float*)d_in[2];
    const float* bq     = (const float*)d_in[3];
    const float* Wk     = (const float*)d_in[4];
    const float* bk     = (const float*)d_in[5];
    const float* Wv     = (const float*)d_in[6];
    const float* bv     = (const float*)d_in[7];
    const float* Wo     = (const float*)d_in[8];
    const float* bo     = (const float*)d_in[9];
    float* out = (float*)d_out;

    char* ws = (char*)d_ws;
    size_t off = 0;
    auto alloc = [&](size_t bytes) -> char* {
        char* p = ws + off;
        off += (bytes + 255) & ~(size_t)255;
        return p;
    };
    short* inA   = (short*)alloc(4194304ull * 2);
    short* inRel = (short*)alloc(4194304ull * 2);
    short* WqT   = (short*)alloc(1048576ull * 2);   // WqT/WkT/WvT contiguous ->
    short* WkT   = (short*)alloc(1048576ull * 2);   // concat B for fused GEMMs
    short* WvT   = (short*)alloc(1048576ull * 2);
    short* WoT   = (short*)alloc(1048576ull * 2);
    short* Qw    = (short*)alloc(4194304ull * 2);
    short* Kw    = (short*)alloc(4194304ull * 2);
    short* Vtw   = (short*)alloc(4194304ull * 2);
    short* posQw = (short*)alloc(4194304ull * 2);
    short* posKw = (short*)alloc(4194304ull * 2);
    short* p2cW  = (short*)alloc(33554432ull * 2);
    short* attnW = (short*)alloc(4194304ull * 2);
    int*   ftabW = (int*)alloc(4096);
    // total ws: ~142 MB (c2p full matrix eliminated — computed in attn)

    // prep
    conv_pair<<<4096, 256, 0, stream>>>(inputs, rel, inA, inRel);
    wtrans<<<dim3(16, 16, 4), 256, 0, stream>>>(Wq, Wk, Wv, Wo, WqT, WkT, WvT, WoT);
    ftab_build<<<4, 256, 0, stream>>>(ftabW);

    // fused QKV projection (N=3072) and posQ/posK projection (N=2048)
    gemm_nt<4><<<dim3(32, 24), 256, 0, stream>>>(inA, 0, 1024, WqT, 0, 1024,
                                                 Qw, Kw, Vtw, 0, 0, bq, bk, bv, 1024);
    gemm_nt<5><<<dim3(32, 16), 256, 0, stream>>>(inRel, 0, 1024, WqT, 0, 1024,
                                                 posQw, posKw, nullptr, 0, 0, bq, bk, nullptr, 1024);

    // score GEMM (p2c only now): p2cT = posQ @ K^T  (batched over bh)
    gemm_nt<1><<<dim3(4, 4, 128), 256, 0, stream>>>(posQw, 32768, 64, Kw, 32768, 64,
                                                    p2cW, nullptr, nullptr, 262144, 512,
                                                    nullptr, nullptr, nullptr, 64);

    // in-place pre-gather: p2cW[bh][q][k] := p2cW[bh][f(q-k)][k]  (vector writes)
    relgather<<<dim3(16, 128), 256, 0, stream>>>(p2cW, ftabW);

    // fused c2p-GEMM + scores + gather + softmax + PV
    attn_fused<<<4096, 256, 0, stream>>>(Qw, Kw, Vtw, posKw, p2cW, ftabW, attnW);

    // output projection (fp32 out + bias)
    gemm_nt<2><<<dim3(32, 8), 256, 0, stream>>>(attnW, 0, 1024, WoT, 0, 1024,
                                                out, nullptr, nullptr, 0, 1024, bo, nullptr, nullptr, 1024);
}

// Round 8
// 250.450 us; speedup vs baseline: 1.0700x; 1.0700x over previous
//
#include <hip/hip_runtime.h>

#define NUM_HEADS 16
#define HEAD_DIM  64
#define HIDDEN    1024
#define SEQ       512
#define BATCH     8
#define NBH       128      // BATCH*NUM_HEADS
#define POSN      512      // 2*BUCKET
#define SCALE_F   0.07216878364870323f   // 1/sqrt(3*HEAD_DIM)

typedef __attribute__((ext_vector_type(8))) short  short8;
typedef __attribute__((ext_vector_type(4))) short  short4_t;
typedef __attribute__((ext_vector_type(4))) float  floatx4;

// async global->LDS, 16B per lane (wave-uniform base + lane*16 dest)
#define GLDS16(gsrc, ldst) \
    __builtin_amdgcn_global_load_lds((const __attribute__((address_space(1))) void*)(gsrc), \
                                     (__attribute__((address_space(3))) void*)(ldst), 16, 0, 0)

__device__ __forceinline__ float bits2f(short s) {
    union { unsigned u; float f; } x;
    x.u = ((unsigned)(unsigned short)s) << 16;
    return x.f;
}
__device__ __forceinline__ short f2bits(float f) {
    union { float f; unsigned u; } x;
    x.f = f;
    unsigned r = x.u + 0x7fffu + ((x.u >> 16) & 1u);
    return (short)(r >> 16);
}

// ---------------------------------------------------------------------------
// prep: fp32 -> bf16 conversion for inputs and rel_embeddings
// ---------------------------------------------------------------------------
__global__ void conv_pair(const float* __restrict__ a, const float* __restrict__ b,
                          short* __restrict__ oa, short* __restrict__ ob)
{
    const int idx = blockIdx.x * 256 + threadIdx.x;    // one float4 each
    floatx4 va = ((const floatx4*)a)[idx];
    floatx4 vb = ((const floatx4*)b)[idx];
    short4_t ra, rb;
#pragma unroll
    for (int i = 0; i < 4; i++) { ra[i] = f2bits(va[i]); rb[i] = f2bits(vb[i]); }
    ((short4_t*)oa)[idx] = ra;
    ((short4_t*)ob)[idx] = rb;
}

// ---------------------------------------------------------------------------
// prep: transpose + convert the 4 weight matrices [1024][1024] -> bf16 [n][c]
// ---------------------------------------------------------------------------
__global__ void wtrans(const float* __restrict__ w0, const float* __restrict__ w1,
                       const float* __restrict__ w2, const float* __restrict__ w3,
                       short* __restrict__ o0, short* __restrict__ o1,
                       short* __restrict__ o2, short* __restrict__ o3)
{
    __shared__ float tile[64][65];
    const int z = blockIdx.z;
    const float* src = (z == 0) ? w0 : (z == 1) ? w1 : (z == 2) ? w2 : w3;
    short*       dst = (z == 0) ? o0 : (z == 1) ? o1 : (z == 2) ? o2 : o3;
    const int c0 = blockIdx.x * 64, n0 = blockIdx.y * 64;
    const int t = threadIdx.x;
#pragma unroll
    for (int j = 0; j < 16; j++) {
        const int e = t + j * 256;
        tile[e >> 6][e & 63] = src[(long)(c0 + (e >> 6)) * 1024 + n0 + (e & 63)];
    }
    __syncthreads();
#pragma unroll
    for (int j = 0; j < 16; j++) {
        const int e = t + j * 256;
        dst[(long)(n0 + (e >> 6)) * 1024 + c0 + (e & 63)] = f2bits(tile[e & 63][e >> 6]);
    }
}

// ---------------------------------------------------------------------------
// prep: 1-D log-bucket table  ftab[delta+511] = clip(bucket(delta)+256, 0, 511)
// ---------------------------------------------------------------------------
__global__ void ftab_build(int* __restrict__ ftab)
{
    const int i = blockIdx.x * 256 + threadIdx.x;
    if (i >= 1023) return;
    const int delta = i - 511;
    const float Cf = (float)log(511.0 / 128.0);
    float absp = (delta < 128 && delta > -128) ? 127.0f : fabsf((float)delta);
    float bucket;
    if (absp <= 128.0f) {
        bucket = (float)delta;
    } else {
        float lp = ceilf((logf(absp * (1.0f / 128.0f)) * 127.0f) / Cf) + 128.0f;
        bucket = (delta > 0) ? lp : -lp;
    }
    int bi = (int)bucket + 256;
    bi = min(max(bi, 0), 511);
    ftab[i] = bi;
}

// ---------------------------------------------------------------------------
// Generic NT GEMM: C[m,n] = sum_k A[m,k] * BT[n,k]   (bf16 in, fp32 acc)
// tile 128x128, BK=64, 256 threads (4 waves, 2x2), 16x16x32 bf16 MFMA
// Staging via global_load_lds width=16: linear LDS dest, inverse-swizzled
// global source chunk (cc = pc ^ (row&7)); swizzled LDS reads unchanged.
// MODE 1: plain -> bf16 out row-major, batched by z; z<128 uses (A,BT),
//         z>=128 uses (O1,O2) as the A/B pair (merged score GEMMs)
// MODE 2: final -> fp32 out row-major + bias b0 (O0)
// MODE 4: QKV   -> n<1024: Q [b,h,s,d]+b0 (O0); n<2048: K +b1 (O1);
//                  else:   V [b,h,d,s]+b2 (O2)
// MODE 5: posQK -> n<1024: posQ [b,h,p,d]+b0 (O0); else posK +b1 (O1)
// ---------------------------------------------------------------------------
template<int MODE>
__global__ __launch_bounds__(256)
void gemm_nt(const short* __restrict__ A, long aBatch, int lda,
             const short* __restrict__ BT, long bBatch, int ldb,
             void* __restrict__ O0, void* __restrict__ O1, void* __restrict__ O2,
             long oBatch, int ldo,
             const float* __restrict__ b0, const float* __restrict__ b1,
             const float* __restrict__ b2, int Kd)
{
    __shared__ __align__(16) short As[128 * 64];
    __shared__ __align__(16) short Bs[128 * 64];
    const int z = blockIdx.z;
    const short* Ab;
    const short* Bb;
    if (MODE == 1 && z >= 128) {
        Ab = (const short*)O1 + (long)(z - 128) * aBatch;
        Bb = (const short*)O2 + (long)(z - 128) * bBatch;
    } else {
        Ab = A + (long)z * aBatch;
        Bb = BT + (long)z * bBatch;
    }
    const int m0 = blockIdx.x * 128, n0 = blockIdx.y * 128;
    const int t = threadIdx.x;
    const int l = t & 63, w = t >> 6;
    const int wm = w >> 1, wn = w & 1;
    const int lr = l & 15, lg = l >> 4;

    floatx4 acc[4][4];
#pragma unroll
    for (int i = 0; i < 4; i++)
#pragma unroll
        for (int j = 0; j < 4; j++) acc[i][j] = (floatx4){0.f, 0.f, 0.f, 0.f};

    for (int k0 = 0; k0 < Kd; k0 += 64) {
        __syncthreads();
        // async staging: 1024 16B chunks per matrix; wave w owns chunks
        // [w*256, w*256+256); LDS linear, global source inverse-swizzled
#pragma unroll
        for (int j = 0; j < 4; j++) {
            const int c = (w * 4 + j) * 64 + l;   // 0..1023
            const int row = c >> 3, pc = c & 7;
            const int cc = pc ^ (row & 7);
            GLDS16(Ab + (long)(m0 + row) * lda + k0 + cc * 8, As + c * 8);
            GLDS16(Bb + (long)(n0 + row) * ldb + k0 + cc * 8, Bs + c * 8);
        }
        __syncthreads();
#pragma unroll
        for (int ks = 0; ks < 2; ks++) {
            short8 af[4], bfr[4];
#pragma unroll
            for (int i = 0; i < 4; i++) {
                const int mr = wm * 64 + i * 16 + lr;
                af[i] = *(const short8*)((char*)As + mr * 128 + (((ks * 4 + lg) ^ (mr & 7)) * 16));
                const int nr = wn * 64 + i * 16 + lr;
                bfr[i] = *(const short8*)((char*)Bs + nr * 128 + (((ks * 4 + lg) ^ (nr & 7)) * 16));
            }
#pragma unroll
            for (int i = 0; i < 4; i++)
#pragma unroll
                for (int j = 0; j < 4; j++)
                    acc[i][j] = __builtin_amdgcn_mfma_f32_16x16x32_bf16(af[i], bfr[j], acc[i][j], 0, 0, 0);
        }
    }

#pragma unroll
    for (int i = 0; i < 4; i++) {
#pragma unroll
        for (int j = 0; j < 4; j++) {
#pragma unroll
            for (int e = 0; e < 4; e++) {
                const int mg = m0 + wm * 64 + i * 16 + lg * 4 + e;
                const int ng = n0 + wn * 64 + j * 16 + lr;
                float v = acc[i][j][e];
                if (MODE == 1) {
                    ((short*)O0)[(long)z * oBatch + (long)mg * ldo + ng] = f2bits(v);
                } else if (MODE == 2) {
                    ((float*)O0)[(long)mg * ldo + ng] = v + b0[ng];
                } else if (MODE == 4) {
                    const int mat = ng >> 10, hh = ng & 1023, h = hh >> 6, d = hh & 63;
                    const int b = mg >> 9, s = mg & 511;
                    v += (mat == 0 ? b0 : mat == 1 ? b1 : b2)[hh];
                    short* dst = (short*)(mat == 0 ? O0 : mat == 1 ? O1 : O2);
                    if (mat == 2)
                        dst[((long)(b * NUM_HEADS + h) * HEAD_DIM + d) * SEQ + s] = f2bits(v);
                    else
                        dst[((long)(b * NUM_HEADS + h) * SEQ + s) * HEAD_DIM + d] = f2bits(v);
                } else {  // MODE 5
                    const int mat = ng >> 10, hh = ng & 1023, h = hh >> 6, d = hh & 63;
                    const int b = mg >> 9, s = mg & 511;
                    v += (mat == 0 ? b0 : b1)[hh];
                    short* dst = (short*)(mat == 0 ? O0 : O1);
                    dst[((long)(b * NUM_HEADS + h) * SEQ + s) * HEAD_DIM + d] = f2bits(v);
                }
            }
        }
    }
}

// ---------------------------------------------------------------------------
// relgather: IN-PLACE relayout  buf[bh][q][k] := buf[bh][f(q-k)][k]
// (bit-exact bf16 copy). Block = (k-stripe of 32, bh). Stage the whole
// 512x32 stripe in LDS first (read-set == write-set -> in-place safe);
// vector short8 writes.
// ---------------------------------------------------------------------------
__global__ __launch_bounds__(256, 4)
void relgather(short* __restrict__ buf, const int* __restrict__ ftab)
{
    __shared__ __align__(16) short pcs[512 * 32];   // 32 KB
    __shared__ short ft[1024];
    const int k0 = blockIdx.x * 32;
    const int bh = blockIdx.y;
    const int t = threadIdx.x;
    for (int i = t; i < 1024; i += 256) ft[i] = (short)((i < 1023) ? ftab[i] : 0);
    short* base = buf + (long)bh * SEQ * POSN;
    // stage: 512 rows x 64B (4 chunks of 16B) = 2048 chunks
#pragma unroll
    for (int j = 0; j < 8; j++) {
        const int chunk = t + j * 256;
        const int row = chunk >> 2, cc = chunk & 3;
        short8 v = *(const short8*)(base + (long)row * POSN + k0 + cc * 8);
        *(short8*)(pcs + row * 32 + cc * 8) = v;
    }
    __syncthreads();
    // write: 512 q-rows x 4 chunks of 8 = 2048 tasks, vector stores
#pragma unroll
    for (int j = 0; j < 8; j++) {
        const int task = t + j * 256;
        const int q = task >> 2, kc = task & 3;
        short8 v;
#pragma unroll
        for (int i = 0; i < 8; i++) {
            const int k = k0 + kc * 8 + i;
            const int fk = (int)ft[q - k + 511];
            v[i] = pcs[fk * 32 + kc * 8 + i];
        }
        *(short8*)(base + (long)q * POSN + k0 + kc * 8) = v;
    }
}

// ---------------------------------------------------------------------------
// Fused attention per (b,h, 32-row q-tile). 4 waves, 3 barriers.
//   Round-6 lean structure, q-tile doubled 16->32 to halve K/Vt re-reads
//   (the measured L2/L3 traffic bottleneck: 663->401 MB).
//   Staging via global_load_lds; c2p gathered from LDS, p2c linear from LDS.
//   Scores acc[2][8] (64 f32/lane); wave w owns k in [w*128, w*128+128).
//   PV: wave w owns OUTPUT dims d in [w*16, w*16+16) -> no cross-wave reduce.
//   P-tile aliases c2pS (barrier-separated).
// LDS ~68.6 KB -> 2 blocks/CU.
// ---------------------------------------------------------------------------
__global__ __launch_bounds__(256, 2)
void attn_fused(const short* __restrict__ Q, const short* __restrict__ K,
                const short* __restrict__ Vt,
                const short* __restrict__ c2pf, const short* __restrict__ Gp2c,
                const int* __restrict__ ftab,
                short* __restrict__ attnO)
{
    __shared__ __align__(16) short c2pS[32 * 512];  // phase 1: c2p rows; phase 2: P tile
    __shared__ __align__(16) short p2cS[32 * 512];  // p2c' rows (linear [q][k])
    __shared__ float red[2][4][32];
    __shared__ short ft[1024];

    // XCD-chunked swizzle: 2048 blocks, blocks of one bh land on one XCD
    const int lin  = blockIdx.x;
    const int lin2 = (lin & 7) * 256 + (lin >> 3);
    const int bh = lin2 >> 4, qt = lin2 & 15;
    const int q0 = qt * 32;
    const int t = threadIdx.x, l = t & 63, w = t >> 6;
    const int lr = l & 15, lg = l >> 4;
    const long pbase = (long)bh * SEQ * HEAD_DIM;
    const short* Qb  = Q  + pbase;
    const short* Kb  = K  + pbase;
    const short* Vtb = Vt + pbase;
    const short* c2pb = c2pf + (long)bh * SEQ * POSN;
    const short* Gb   = Gp2c + (long)bh * SEQ * SEQ;

    for (int i = t; i < 1024; i += 256) ft[i] = (short)((i < 1023) ? ftab[i] : 0);

    // ---- stage 32 c2p rows + 32 p2c' rows async (2048 16B chunks each) ----
#pragma unroll
    for (int j = 0; j < 8; j++) {
        const int c = w * 512 + j * 64 + l;   // 0..2047
        const int row = c >> 6, cc = c & 63;
        GLDS16(c2pb + (long)(q0 + row) * POSN + cc * 8, c2pS + c * 8);
        GLDS16(Gb + (long)(q0 + row) * SEQ + cc * 8, p2cS + c * 8);
    }

    // ---- Q fragments ----
    short8 aq[2][2];
#pragma unroll
    for (int mt = 0; mt < 2; mt++)
#pragma unroll
        for (int ks = 0; ks < 2; ks++)
            aq[mt][ks] = *(const short8*)(Qb + (q0 + mt * 16 + lr) * 64 + ks * 32 + lg * 8);

    floatx4 acc[2][8];
#pragma unroll
    for (int mt = 0; mt < 2; mt++)
#pragma unroll
        for (int nt = 0; nt < 8; nt++) acc[mt][nt] = (floatx4){0.f, 0.f, 0.f, 0.f};

    // ---- QK^T (K straight from global/L2, shared across mt) ----
#pragma unroll
    for (int nt = 0; nt < 8; nt++) {
        const int kr = w * 128 + nt * 16 + lr;
        short8 kb0 = *(const short8*)(Kb + kr * 64 + lg * 8);
        short8 kb1 = *(const short8*)(Kb + kr * 64 + 32 + lg * 8);
#pragma unroll
        for (int mt = 0; mt < 2; mt++) {
            acc[mt][nt] = __builtin_amdgcn_mfma_f32_16x16x32_bf16(aq[mt][0], kb0, acc[mt][nt], 0, 0, 0);
            acc[mt][nt] = __builtin_amdgcn_mfma_f32_16x16x32_bf16(aq[mt][1], kb1, acc[mt][nt], 0, 0, 0);
        }
    }

    __syncthreads();   // staging (vmcnt) + ft visible

    // ---- add c2p (LDS gather) + p2c (LDS linear), scale ----
#pragma unroll
    for (int mt = 0; mt < 2; mt++)
#pragma unroll
        for (int nt = 0; nt < 8; nt++) {
            const int k = w * 128 + nt * 16 + lr;
#pragma unroll
            for (int e = 0; e < 4; e++) {
                const int r = mt * 16 + lg * 4 + e;
                const int fk = (int)ft[q0 + r - k + 511];
                acc[mt][nt][e] = (acc[mt][nt][e] + bits2f(c2pS[r * 512 + fk])
                                                 + bits2f(p2cS[r * 512 + k])) * SCALE_F;
            }
        }

    // ---- wave-local row max -> LDS ----
#pragma unroll
    for (int mt = 0; mt < 2; mt++)
#pragma unroll
        for (int e = 0; e < 4; e++) {
            float m = acc[mt][0][e];
#pragma unroll
            for (int nt = 1; nt < 8; nt++) m = fmaxf(m, acc[mt][nt][e]);
            m = fmaxf(m, __shfl_xor(m, 1));
            m = fmaxf(m, __shfl_xor(m, 2));
            m = fmaxf(m, __shfl_xor(m, 4));
            m = fmaxf(m, __shfl_xor(m, 8));
            red[0][w][mt * 16 + lg * 4 + e] = m;
        }
    __syncthreads();   // all c2pS gather-reads done; safe to alias as P tile

    // ---- combine max, exp, sum, write P tile (aliases c2pS) ----
#pragma unroll
    for (int mt = 0; mt < 2; mt++)
#pragma unroll
        for (int e = 0; e < 4; e++) {
            const int r = mt * 16 + lg * 4 + e;
            const float m = fmaxf(fmaxf(red[0][0][r], red[0][1][r]),
                                  fmaxf(red[0][2][r], red[0][3][r]));
            float s = 0.f;
#pragma unroll
            for (int nt = 0; nt < 8; nt++) {
                float p = __expf(acc[mt][nt][e] - m);
                acc[mt][nt][e] = p;
                s += p;
            }
            s += __shfl_xor(s, 1); s += __shfl_xor(s, 2);
            s += __shfl_xor(s, 4); s += __shfl_xor(s, 8);
            red[1][w][r] = s;
#pragma unroll
            for (int nt = 0; nt < 8; nt++) {
                const int kcol = w * 128 + nt * 16 + lr;
                int byte = r * 1024 + kcol * 2;
                byte ^= (r & 7) << 4;
                *(short*)((char*)c2pS + byte) = f2bits(acc[mt][nt][e]);
            }
        }
    __syncthreads();

    // ---- PV: wave w owns d in [w*16, w*16+16), k-loop over all 512 ----
    floatx4 accO[2];
    accO[0] = (floatx4){0.f, 0.f, 0.f, 0.f};
    accO[1] = (floatx4){0.f, 0.f, 0.f, 0.f};
#pragma unroll
    for (int ks = 0; ks < 16; ks++) {
        short8 vb = *(const short8*)(Vtb + (long)(w * 16 + lr) * SEQ + ks * 32 + lg * 8);
#pragma unroll
        for (int mt = 0; mt < 2; mt++) {
            const int qr = mt * 16 + lr;
            int byte = qr * 1024 + (ks * 32 + lg * 8) * 2;
            byte ^= (qr & 7) << 4;
            short8 pa = *(const short8*)((char*)c2pS + byte);
            accO[mt] = __builtin_amdgcn_mfma_f32_16x16x32_bf16(pa, vb, accO[mt], 0, 0, 0);
        }
    }

    // ---- normalize + write ----
    const int b = bh >> 4, h = bh & 15;
#pragma unroll
    for (int mt = 0; mt < 2; mt++)
#pragma unroll
        for (int e = 0; e < 4; e++) {
            const int r = mt * 16 + lg * 4 + e;
            const float rs = red[1][0][r] + red[1][1][r] + red[1][2][r] + red[1][3][r];
            const float v = accO[mt][e] / rs;
            attnO[((long)(b * SEQ + q0 + r)) * HIDDEN + h * HEAD_DIM + w * 16 + lr] = f2bits(v);
        }
}

// ---------------------------------------------------------------------------
extern "C" void kernel_launch(void* const* d_in, const int* in_sizes, int n_in,
                              void* d_out, int out_size, void* d_ws, size_t ws_size,
                              hipStream_t stream)
{
    const float* inputs = (const float*)d_in[0];
    const float* rel    = (const float*)d_in[1];
    const float* Wq     = (const float*)d_in[2];
    const float* bq     = (const float*)d_in[3];
    const float* Wk     = (const float*)d_in[4];
    const float* bk     = (const float*)d_in[5];
    const float* Wv     = (const float*)d_in[6];
    const float* bv     = (const float*)d_in[7];
    const float* Wo     = (const float*)d_in[8];
    const float* bo     = (const float*)d_in[9];
    float* out = (float*)d_out;

    char* ws = (char*)d_ws;
    size_t off = 0;
    auto alloc = [&](size_t bytes) -> char* {
        char* p = ws + off;
        off += (bytes + 255) & ~(size_t)255;
        return p;
    };
    short* inA   = (short*)alloc(4194304ull * 2);
    short* inRel = (short*)alloc(4194304ull * 2);
    short* WqT   = (short*)alloc(1048576ull * 2);   // WqT/WkT/WvT contiguous ->
    short* WkT   = (short*)alloc(1048576ull * 2);   // concat B for fused GEMMs
    short* WvT   = (short*)alloc(1048576ull * 2);
    short* WoT   = (short*)alloc(1048576ull * 2);
    short* Qw    = (short*)alloc(4194304ull * 2);
    short* Kw    = (short*)alloc(4194304ull * 2);
    short* Vtw   = (short*)alloc(4194304ull * 2);
    short* posQw = (short*)alloc(4194304ull * 2);
    short* posKw = (short*)alloc(4194304ull * 2);
    short* c2pW  = (short*)alloc(33554432ull * 2);  // c2pW/p2cW contiguous ->
    short* p2cW  = (short*)alloc(33554432ull * 2);  // merged score-GEMM output
    short* attnW = (short*)alloc(4194304ull * 2);
    int*   ftabW = (int*)alloc(4096);
    // total ws: ~209.7 MB (known-safe footprint)

    // prep
    conv_pair<<<4096, 256, 0, stream>>>(inputs, rel, inA, inRel);
    wtrans<<<dim3(16, 16, 4), 256, 0, stream>>>(Wq, Wk, Wv, Wo, WqT, WkT, WvT, WoT);
    ftab_build<<<4, 256, 0, stream>>>(ftabW);

    // fused QKV projection (N=3072) and posQ/posK projection (N=2048)
    gemm_nt<4><<<dim3(32, 24), 256, 0, stream>>>(inA, 0, 1024, WqT, 0, 1024,
                                                 Qw, Kw, Vtw, 0, 0, bq, bk, bv, 1024);
    gemm_nt<5><<<dim3(32, 16), 256, 0, stream>>>(inRel, 0, 1024, WqT, 0, 1024,
                                                 posQw, posKw, nullptr, 0, 0, bq, bk, nullptr, 1024);

    // merged score GEMMs: z<128 -> c2p = Q@posK^T; z>=128 -> p2cT = posQ@K^T
    gemm_nt<1><<<dim3(4, 4, 256), 256, 0, stream>>>(Qw, 32768, 64, posKw, 32768, 64,
                                                    c2pW, posQw, Kw, 262144, 512,
                                                    nullptr, nullptr, nullptr, 64);

    // in-place pre-gather: p2cW[bh][q][k] := p2cW[bh][f(q-k)][k]  (vector writes)
    relgather<<<dim3(16, 128), 256, 0, stream>>>(p2cW, ftabW);

    // fused scores+gather+softmax+PV (q-tile 32)
    attn_fused<<<2048, 256, 0, stream>>>(Qw, Kw, Vtw, c2pW, p2cW, ftabW, attnW);

    // output projection (fp32 out + bias)
    gemm_nt<2><<<dim3(32, 8), 256, 0, stream>>>(attnW, 0, 1024, WoT, 0, 1024,
                                                out, nullptr, nullptr, 0, 1024, bo, nullptr, nullptr, 1024);
}

// Round 9
// 247.139 us; speedup vs baseline: 1.0843x; 1.0134x over previous
//
#include <hip/hip_runtime.h>

#define NUM_HEADS 16
#define HEAD_DIM  64
#define HIDDEN    1024
#define SEQ       512
#define BATCH     8
#define NBH       128      // BATCH*NUM_HEADS
#define POSN      512      // 2*BUCKET
#define SCALE_F   0.07216878364870323f   // 1/sqrt(3*HEAD_DIM)

typedef __attribute__((ext_vector_type(8))) short  short8;
typedef __attribute__((ext_vector_type(4))) short  short4_t;
typedef __attribute__((ext_vector_type(4))) float  floatx4;

// async global->LDS, 16B per lane (wave-uniform base + lane*16 dest)
#define GLDS16(gsrc, ldst) \
    __builtin_amdgcn_global_load_lds((const __attribute__((address_space(1))) void*)(gsrc), \
                                     (__attribute__((address_space(3))) void*)(ldst), 16, 0, 0)

__device__ __forceinline__ float bits2f(short s) {
    union { unsigned u; float f; } x;
    x.u = ((unsigned)(unsigned short)s) << 16;
    return x.f;
}
__device__ __forceinline__ short f2bits(float f) {
    union { float f; unsigned u; } x;
    x.f = f;
    unsigned r = x.u + 0x7fffu + ((x.u >> 16) & 1u);
    return (short)(r >> 16);
}

// ---------------------------------------------------------------------------
// prep: fp32 -> bf16 conversion for inputs and rel_embeddings
// ---------------------------------------------------------------------------
__global__ void conv_pair(const float* __restrict__ a, const float* __restrict__ b,
                          short* __restrict__ oa, short* __restrict__ ob)
{
    const int idx = blockIdx.x * 256 + threadIdx.x;    // one float4 each
    floatx4 va = ((const floatx4*)a)[idx];
    floatx4 vb = ((const floatx4*)b)[idx];
    short4_t ra, rb;
#pragma unroll
    for (int i = 0; i < 4; i++) { ra[i] = f2bits(va[i]); rb[i] = f2bits(vb[i]); }
    ((short4_t*)oa)[idx] = ra;
    ((short4_t*)ob)[idx] = rb;
}

// ---------------------------------------------------------------------------
// prep: transpose + convert the 4 weight matrices [1024][1024] -> bf16 [n][c]
// ---------------------------------------------------------------------------
__global__ void wtrans(const float* __restrict__ w0, const float* __restrict__ w1,
                       const float* __restrict__ w2, const float* __restrict__ w3,
                       short* __restrict__ o0, short* __restrict__ o1,
                       short* __restrict__ o2, short* __restrict__ o3)
{
    __shared__ float tile[64][65];
    const int z = blockIdx.z;
    const float* src = (z == 0) ? w0 : (z == 1) ? w1 : (z == 2) ? w2 : w3;
    short*       dst = (z == 0) ? o0 : (z == 1) ? o1 : (z == 2) ? o2 : o3;
    const int c0 = blockIdx.x * 64, n0 = blockIdx.y * 64;
    const int t = threadIdx.x;
#pragma unroll
    for (int j = 0; j < 16; j++) {
        const int e = t + j * 256;
        tile[e >> 6][e & 63] = src[(long)(c0 + (e >> 6)) * 1024 + n0 + (e & 63)];
    }
    __syncthreads();
#pragma unroll
    for (int j = 0; j < 16; j++) {
        const int e = t + j * 256;
        dst[(long)(n0 + (e >> 6)) * 1024 + c0 + (e & 63)] = f2bits(tile[e & 63][e >> 6]);
    }
}

// ---------------------------------------------------------------------------
// prep: 1-D log-bucket table  ftab[delta+511] = clip(bucket(delta)+256, 0, 511)
// ---------------------------------------------------------------------------
__global__ void ftab_build(int* __restrict__ ftab)
{
    const int i = blockIdx.x * 256 + threadIdx.x;
    if (i >= 1023) return;
    const int delta = i - 511;
    const float Cf = (float)log(511.0 / 128.0);
    float absp = (delta < 128 && delta > -128) ? 127.0f : fabsf((float)delta);
    float bucket;
    if (absp <= 128.0f) {
        bucket = (float)delta;
    } else {
        float lp = ceilf((logf(absp * (1.0f / 128.0f)) * 127.0f) / Cf) + 128.0f;
        bucket = (delta > 0) ? lp : -lp;
    }
    int bi = (int)bucket + 256;
    bi = min(max(bi, 0), 511);
    ftab[i] = bi;
}

// ---------------------------------------------------------------------------
// Generic NT GEMM: C[m,n] = sum_k A[m,k] * BT[n,k]   (bf16 in, fp32 acc)
// tile 128x128, BK=64, 256 threads (4 waves, 2x2), 16x16x32 bf16 MFMA
// Staging via global_load_lds width=16: linear LDS dest, inverse-swizzled
// global source chunk (cc = pc ^ (row&7)); swizzled LDS reads unchanged.
// MODE 1: plain -> bf16 out row-major, batched by z; z<128 uses (A,BT),
//         z>=128 uses (O1,O2) as the A/B pair (merged score GEMMs)
// MODE 2: final -> fp32 out row-major + bias b0 (O0)
// MODE 4: QKV   -> n<1024: Q [b,h,s,d]+b0 (O0); n<2048: K +b1 (O1);
//                  else:   V [b,h,d,s]+b2 (O2)
// MODE 5: posQK -> n<1024: posQ [b,h,p,d]+b0 (O0); else posK +b1 (O1)
// ---------------------------------------------------------------------------
template<int MODE>
__global__ __launch_bounds__(256)
void gemm_nt(const short* __restrict__ A, long aBatch, int lda,
             const short* __restrict__ BT, long bBatch, int ldb,
             void* __restrict__ O0, void* __restrict__ O1, void* __restrict__ O2,
             long oBatch, int ldo,
             const float* __restrict__ b0, const float* __restrict__ b1,
             const float* __restrict__ b2, int Kd)
{
    __shared__ __align__(16) short As[128 * 64];
    __shared__ __align__(16) short Bs[128 * 64];
    const int z = blockIdx.z;
    const short* Ab;
    const short* Bb;
    if (MODE == 1 && z >= 128) {
        Ab = (const short*)O1 + (long)(z - 128) * aBatch;
        Bb = (const short*)O2 + (long)(z - 128) * bBatch;
    } else {
        Ab = A + (long)z * aBatch;
        Bb = BT + (long)z * bBatch;
    }
    const int m0 = blockIdx.x * 128, n0 = blockIdx.y * 128;
    const int t = threadIdx.x;
    const int l = t & 63, w = t >> 6;
    const int wm = w >> 1, wn = w & 1;
    const int lr = l & 15, lg = l >> 4;

    floatx4 acc[4][4];
#pragma unroll
    for (int i = 0; i < 4; i++)
#pragma unroll
        for (int j = 0; j < 4; j++) acc[i][j] = (floatx4){0.f, 0.f, 0.f, 0.f};

    for (int k0 = 0; k0 < Kd; k0 += 64) {
        __syncthreads();
        // async staging: 1024 16B chunks per matrix; wave w owns chunks
        // [w*256, w*256+256); LDS linear, global source inverse-swizzled
#pragma unroll
        for (int j = 0; j < 4; j++) {
            const int c = (w * 4 + j) * 64 + l;   // 0..1023
            const int row = c >> 3, pc = c & 7;
            const int cc = pc ^ (row & 7);
            GLDS16(Ab + (long)(m0 + row) * lda + k0 + cc * 8, As + c * 8);
            GLDS16(Bb + (long)(n0 + row) * ldb + k0 + cc * 8, Bs + c * 8);
        }
        __syncthreads();
#pragma unroll
        for (int ks = 0; ks < 2; ks++) {
            short8 af[4], bfr[4];
#pragma unroll
            for (int i = 0; i < 4; i++) {
                const int mr = wm * 64 + i * 16 + lr;
                af[i] = *(const short8*)((char*)As + mr * 128 + (((ks * 4 + lg) ^ (mr & 7)) * 16));
                const int nr = wn * 64 + i * 16 + lr;
                bfr[i] = *(const short8*)((char*)Bs + nr * 128 + (((ks * 4 + lg) ^ (nr & 7)) * 16));
            }
#pragma unroll
            for (int i = 0; i < 4; i++)
#pragma unroll
                for (int j = 0; j < 4; j++)
                    acc[i][j] = __builtin_amdgcn_mfma_f32_16x16x32_bf16(af[i], bfr[j], acc[i][j], 0, 0, 0);
        }
    }

#pragma unroll
    for (int i = 0; i < 4; i++) {
#pragma unroll
        for (int j = 0; j < 4; j++) {
#pragma unroll
            for (int e = 0; e < 4; e++) {
                const int mg = m0 + wm * 64 + i * 16 + lg * 4 + e;
                const int ng = n0 + wn * 64 + j * 16 + lr;
                float v = acc[i][j][e];
                if (MODE == 1) {
                    ((short*)O0)[(long)z * oBatch + (long)mg * ldo + ng] = f2bits(v);
                } else if (MODE == 2) {
                    ((float*)O0)[(long)mg * ldo + ng] = v + b0[ng];
                } else if (MODE == 4) {
                    const int mat = ng >> 10, hh = ng & 1023, h = hh >> 6, d = hh & 63;
                    const int b = mg >> 9, s = mg & 511;
                    v += (mat == 0 ? b0 : mat == 1 ? b1 : b2)[hh];
                    short* dst = (short*)(mat == 0 ? O0 : mat == 1 ? O1 : O2);
                    if (mat == 2)
                        dst[((long)(b * NUM_HEADS + h) * HEAD_DIM + d) * SEQ + s] = f2bits(v);
                    else
                        dst[((long)(b * NUM_HEADS + h) * SEQ + s) * HEAD_DIM + d] = f2bits(v);
                } else {  // MODE 5
                    const int mat = ng >> 10, hh = ng & 1023, h = hh >> 6, d = hh & 63;
                    const int b = mg >> 9, s = mg & 511;
                    v += (mat == 0 ? b0 : b1)[hh];
                    short* dst = (short*)(mat == 0 ? O0 : O1);
                    dst[((long)(b * NUM_HEADS + h) * SEQ + s) * HEAD_DIM + d] = f2bits(v);
                }
            }
        }
    }
}

// ---------------------------------------------------------------------------
// relgather: IN-PLACE relayout  buf[bh][q][k] := buf[bh][f(q-k)][k]
// (bit-exact bf16 copy). Block = (k-stripe of 32, bh). Stage the whole
// 512x32 stripe in LDS first (read-set == write-set -> in-place safe);
// LDS chunk-XOR swizzle (cc ^ (row&3)) breaks the 8-way bank conflict of the
// fk-row gather; vector short8 writes.
// ---------------------------------------------------------------------------
__global__ __launch_bounds__(256, 4)
void relgather(short* __restrict__ buf, const int* __restrict__ ftab)
{
    __shared__ __align__(16) short pcs[512 * 32];   // 32 KB, chunk-swizzled
    __shared__ short ft[1024];
    const int k0 = blockIdx.x * 32;
    const int bh = blockIdx.y;
    const int t = threadIdx.x;
    for (int i = t; i < 1024; i += 256) ft[i] = (short)((i < 1023) ? ftab[i] : 0);
    short* base = buf + (long)bh * SEQ * POSN;
    // stage: 512 rows x 4 chunks of 16B, stored at swizzled chunk cc^(row&3)
#pragma unroll
    for (int j = 0; j < 8; j++) {
        const int chunk = t + j * 256;
        const int row = chunk >> 2, cc = chunk & 3;
        short8 v = *(const short8*)(base + (long)row * POSN + k0 + cc * 8);
        *(short8*)(pcs + row * 32 + (cc ^ (row & 3)) * 8) = v;
    }
    __syncthreads();
    // write: 512 q-rows x 4 chunks of 8 = 2048 tasks, vector stores
#pragma unroll
    for (int j = 0; j < 8; j++) {
        const int task = t + j * 256;
        const int q = task >> 2, kc = task & 3;
        short8 v;
#pragma unroll
        for (int i = 0; i < 8; i++) {
            const int k = k0 + kc * 8 + i;
            const int fk = (int)ft[q - k + 511];
            v[i] = pcs[fk * 32 + (kc ^ (fk & 3)) * 8 + i];
        }
        *(short8*)(base + (long)q * POSN + k0 + kc * 8) = v;
    }
}

// ---------------------------------------------------------------------------
// Fused attention per (b,h, 32-row q-tile). 4 waves, 3 barriers.
//   c2p rows staged via global_load_lds with SOURCE chunk-swizzle
//   (cc ^ (row&7)) so the data-dependent fk-gather is bank-spread (read
//   index fk ^ ((r&7)<<3)).  G (pre-gathered p2c) is read-once ->
//   consumed DIRECTLY from global (32B-contiguous per 16-lane group),
//   no LDS staging.  LDS ~36.5 KB -> 4 blocks/CU (was 2).
//   softmax: shfl within 16-lane groups + tiny LDS cross-wave combine.
//   PV: wave w owns OUTPUT dims d in [w*16, w*16+16) -> no cross-wave reduce.
//   P-tile aliases c2pS (barrier-separated).
// ---------------------------------------------------------------------------
__global__ __launch_bounds__(256, 4)
void attn_fused(const short* __restrict__ Q, const short* __restrict__ K,
                const short* __restrict__ Vt,
                const short* __restrict__ c2pf, const short* __restrict__ Gp2c,
                const int* __restrict__ ftab,
                short* __restrict__ attnO)
{
    __shared__ __align__(16) short c2pS[32 * 512];  // phase 1: c2p (swz); phase 2: P tile
    __shared__ float red[2][4][32];
    __shared__ short ft[1024];

    // XCD-chunked swizzle: 2048 blocks, blocks of one bh land on one XCD
    const int lin  = blockIdx.x;
    const int lin2 = (lin & 7) * 256 + (lin >> 3);
    const int bh = lin2 >> 4, qt = lin2 & 15;
    const int q0 = qt * 32;
    const int t = threadIdx.x, l = t & 63, w = t >> 6;
    const int lr = l & 15, lg = l >> 4;
    const long pbase = (long)bh * SEQ * HEAD_DIM;
    const short* Qb  = Q  + pbase;
    const short* Kb  = K  + pbase;
    const short* Vtb = Vt + pbase;
    const short* c2pb = c2pf + (long)bh * SEQ * POSN;
    const short* Gb   = Gp2c + (long)bh * SEQ * SEQ;

    for (int i = t; i < 1024; i += 256) ft[i] = (short)((i < 1023) ? ftab[i] : 0);

    // ---- stage 32 c2p rows async, source chunk-swizzled (dest linear) ----
#pragma unroll
    for (int j = 0; j < 8; j++) {
        const int c = w * 512 + j * 64 + l;   // 0..2047
        const int row = c >> 6, cc = c & 63;
        GLDS16(c2pb + (long)(q0 + row) * POSN + (cc ^ (row & 7)) * 8, c2pS + c * 8);
    }

    // ---- Q fragments ----
    short8 aq[2][2];
#pragma unroll
    for (int mt = 0; mt < 2; mt++)
#pragma unroll
        for (int ks = 0; ks < 2; ks++)
            aq[mt][ks] = *(const short8*)(Qb + (q0 + mt * 16 + lr) * 64 + ks * 32 + lg * 8);

    floatx4 acc[2][8];
#pragma unroll
    for (int mt = 0; mt < 2; mt++)
#pragma unroll
        for (int nt = 0; nt < 8; nt++) acc[mt][nt] = (floatx4){0.f, 0.f, 0.f, 0.f};

    // ---- QK^T (K straight from global/L2, shared across mt) ----
#pragma unroll
    for (int nt = 0; nt < 8; nt++) {
        const int kr = w * 128 + nt * 16 + lr;
        short8 kb0 = *(const short8*)(Kb + kr * 64 + lg * 8);
        short8 kb1 = *(const short8*)(Kb + kr * 64 + 32 + lg * 8);
#pragma unroll
        for (int mt = 0; mt < 2; mt++) {
            acc[mt][nt] = __builtin_amdgcn_mfma_f32_16x16x32_bf16(aq[mt][0], kb0, acc[mt][nt], 0, 0, 0);
            acc[mt][nt] = __builtin_amdgcn_mfma_f32_16x16x32_bf16(aq[mt][1], kb1, acc[mt][nt], 0, 0, 0);
        }
    }

    __syncthreads();   // staging (vmcnt) + ft visible

    // ---- add c2p (LDS swizzled gather) + G (direct global, coalesced), scale ----
#pragma unroll
    for (int mt = 0; mt < 2; mt++)
#pragma unroll
        for (int nt = 0; nt < 8; nt++) {
            const int k = w * 128 + nt * 16 + lr;
#pragma unroll
            for (int e = 0; e < 4; e++) {
                const int r = mt * 16 + lg * 4 + e;
                const int fk = (int)ft[q0 + r - k + 511];
                acc[mt][nt][e] = (acc[mt][nt][e]
                                  + bits2f(c2pS[r * 512 + (fk ^ ((r & 7) << 3))])
                                  + bits2f(Gb[(long)(q0 + r) * SEQ + k])) * SCALE_F;
            }
        }

    // ---- wave-local row max -> LDS ----
#pragma unroll
    for (int mt = 0; mt < 2; mt++)
#pragma unroll
        for (int e = 0; e < 4; e++) {
            float m = acc[mt][0][e];
#pragma unroll
            for (int nt = 1; nt < 8; nt++) m = fmaxf(m, acc[mt][nt][e]);
            m = fmaxf(m, __shfl_xor(m, 1));
            m = fmaxf(m, __shfl_xor(m, 2));
            m = fmaxf(m, __shfl_xor(m, 4));
            m = fmaxf(m, __shfl_xor(m, 8));
            red[0][w][mt * 16 + lg * 4 + e] = m;
        }
    __syncthreads();   // all c2pS gather-reads done; safe to alias as P tile

    // ---- combine max, exp, sum, write P tile (aliases c2pS) ----
#pragma unroll
    for (int mt = 0; mt < 2; mt++)
#pragma unroll
        for (int e = 0; e < 4; e++) {
            const int r = mt * 16 + lg * 4 + e;
            const float m = fmaxf(fmaxf(red[0][0][r], red[0][1][r]),
                                  fmaxf(red[0][2][r], red[0][3][r]));
            float s = 0.f;
#pragma unroll
            for (int nt = 0; nt < 8; nt++) {
                float p = __expf(acc[mt][nt][e] - m);
                acc[mt][nt][e] = p;
                s += p;
            }
            s += __shfl_xor(s, 1); s += __shfl_xor(s, 2);
            s += __shfl_xor(s, 4); s += __shfl_xor(s, 8);
            red[1][w][r] = s;
#pragma unroll
            for (int nt = 0; nt < 8; nt++) {
                const int kcol = w * 128 + nt * 16 + lr;
                int byte = r * 1024 + kcol * 2;
                byte ^= (r & 7) << 4;
                *(short*)((char*)c2pS + byte) = f2bits(acc[mt][nt][e]);
            }
        }
    __syncthreads();

    // ---- PV: wave w owns d in [w*16, w*16+16), k-loop over all 512 ----
    floatx4 accO[2];
    accO[0] = (floatx4){0.f, 0.f, 0.f, 0.f};
    accO[1] = (floatx4){0.f, 0.f, 0.f, 0.f};
#pragma unroll
    for (int ks = 0; ks < 16; ks++) {
        short8 vb = *(const short8*)(Vtb + (long)(w * 16 + lr) * SEQ + ks * 32 + lg * 8);
#pragma unroll
        for (int mt = 0; mt < 2; mt++) {
            const int qr = mt * 16 + lr;
            int byte = qr * 1024 + (ks * 32 + lg * 8) * 2;
            byte ^= (qr & 7) << 4;
            short8 pa = *(const short8*)((char*)c2pS + byte);
            accO[mt] = __builtin_amdgcn_mfma_f32_16x16x32_bf16(pa, vb, accO[mt], 0, 0, 0);
        }
    }

    // ---- normalize + write ----
    const int b = bh >> 4, h = bh & 15;
#pragma unroll
    for (int mt = 0; mt < 2; mt++)
#pragma unroll
        for (int e = 0; e < 4; e++) {
            const int r = mt * 16 + lg * 4 + e;
            const float rs = red[1][0][r] + red[1][1][r] + red[1][2][r] + red[1][3][r];
            const float v = accO[mt][e] / rs;
            attnO[((long)(b * SEQ + q0 + r)) * HIDDEN + h * HEAD_DIM + w * 16 + lr] = f2bits(v);
        }
}

// ---------------------------------------------------------------------------
extern "C" void kernel_launch(void* const* d_in, const int* in_sizes, int n_in,
                              void* d_out, int out_size, void* d_ws, size_t ws_size,
                              hipStream_t stream)
{
    const float* inputs = (const float*)d_in[0];
    const float* rel    = (const float*)d_in[1];
    const float* Wq     = (const float*)d_in[2];
    const float* bq     = (const float*)d_in[3];
    const float* Wk     = (const float*)d_in[4];
    const float* bk     = (const float*)d_in[5];
    const float* Wv     = (const float*)d_in[6];
    const float* bv     = (const float*)d_in[7];
    const float* Wo     = (const float*)d_in[8];
    const float* bo     = (const float*)d_in[9];
    float* out = (float*)d_out;

    char* ws = (char*)d_ws;
    size_t off = 0;
    auto alloc = [&](size_t bytes) -> char* {
        char* p = ws + off;
        off += (bytes + 255) & ~(size_t)255;
        return p;
    };
    short* inA   = (short*)alloc(4194304ull * 2);
    short* inRel = (short*)alloc(4194304ull * 2);
    short* WqT   = (short*)alloc(1048576ull * 2);   // WqT/WkT/WvT contiguous ->
    short* WkT   = (short*)alloc(1048576ull * 2);   // concat B for fused GEMMs
    short* WvT   = (short*)alloc(1048576ull * 2);
    short* WoT   = (short*)alloc(1048576ull * 2);
    short* Qw    = (short*)alloc(4194304ull * 2);
    short* Kw    = (short*)alloc(4194304ull * 2);
    short* Vtw   = (short*)alloc(4194304ull * 2);
    short* posQw = (short*)alloc(4194304ull * 2);
    short* posKw = (short*)alloc(4194304ull * 2);
    short* c2pW  = (short*)alloc(33554432ull * 2);  // c2pW/p2cW contiguous ->
    short* p2cW  = (short*)alloc(33554432ull * 2);  // merged score-GEMM output
    short* attnW = (short*)alloc(4194304ull * 2);
    int*   ftabW = (int*)alloc(4096);
    // total ws: ~209.7 MB (known-safe footprint)

    // prep
    conv_pair<<<4096, 256, 0, stream>>>(inputs, rel, inA, inRel);
    wtrans<<<dim3(16, 16, 4), 256, 0, stream>>>(Wq, Wk, Wv, Wo, WqT, WkT, WvT, WoT);
    ftab_build<<<4, 256, 0, stream>>>(ftabW);

    // fused QKV projection (N=3072) and posQ/posK projection (N=2048)
    gemm_nt<4><<<dim3(32, 24), 256, 0, stream>>>(inA, 0, 1024, WqT, 0, 1024,
                                                 Qw, Kw, Vtw, 0, 0, bq, bk, bv, 1024);
    gemm_nt<5><<<dim3(32, 16), 256, 0, stream>>>(inRel, 0, 1024, WqT, 0, 1024,
                                                 posQw, posKw, nullptr, 0, 0, bq, bk, nullptr, 1024);

    // merged score GEMMs: z<128 -> c2p = Q@posK^T; z>=128 -> p2cT = posQ@K^T
    gemm_nt<1><<<dim3(4, 4, 256), 256, 0, stream>>>(Qw, 32768, 64, posKw, 32768, 64,
                                                    c2pW, posQw, Kw, 262144, 512,
                                                    nullptr, nullptr, nullptr, 64);

    // in-place pre-gather: p2cW[bh][q][k] := p2cW[bh][f(q-k)][k]  (vector writes)
    relgather<<<dim3(16, 128), 256, 0, stream>>>(p2cW, ftabW);

    // fused scores+gather+softmax+PV (q-tile 32, 4 blocks/CU)
    attn_fused<<<2048, 256, 0, stream>>>(Qw, Kw, Vtw, c2pW, p2cW, ftabW, attnW);

    // output projection (fp32 out + bias)
    gemm_nt<2><<<dim3(32, 8), 256, 0, stream>>>(attnW, 0, 1024, WoT, 0, 1024,
                                                out, nullptr, nullptr, 0, 1024, bo, nullptr, nullptr, 1024);
}

// Round 10
// 218.295 us; speedup vs baseline: 1.2276x; 1.1321x over previous
//
#include <hip/hip_runtime.h>

#define NUM_HEADS 16
#define HEAD_DIM  64
#define HIDDEN    1024
#define SEQ       512
#define BATCH     8
#define NBH       128      // BATCH*NUM_HEADS
#define POSN      512      // 2*BUCKET
#define SCALE_F   0.07216878364870323f   // 1/sqrt(3*HEAD_DIM)

typedef __attribute__((ext_vector_type(8))) short  short8;
typedef __attribute__((ext_vector_type(4))) short  short4_t;
typedef __attribute__((ext_vector_type(4))) float  floatx4;

// async global->LDS, 16B per lane (wave-uniform base + lane*16 dest)
#define GLDS16(gsrc, ldst) \
    __builtin_amdgcn_global_load_lds((const __attribute__((address_space(1))) void*)(gsrc), \
                                     (__attribute__((address_space(3))) void*)(ldst), 16, 0, 0)

__device__ __forceinline__ float bits2f(short s) {
    union { unsigned u; float f; } x;
    x.u = ((unsigned)(unsigned short)s) << 16;
    return x.f;
}
__device__ __forceinline__ short f2bits(float f) {
    union { float f; unsigned u; } x;
    x.f = f;
    unsigned r = x.u + 0x7fffu + ((x.u >> 16) & 1u);
    return (short)(r >> 16);
}

// ---------------------------------------------------------------------------
// prep: fp32 -> bf16 conversion for inputs and rel_embeddings
// ---------------------------------------------------------------------------
__global__ void conv_pair(const float* __restrict__ a, const float* __restrict__ b,
                          short* __restrict__ oa, short* __restrict__ ob)
{
    const int idx = blockIdx.x * 256 + threadIdx.x;    // one float4 each
    floatx4 va = ((const floatx4*)a)[idx];
    floatx4 vb = ((const floatx4*)b)[idx];
    short4_t ra, rb;
#pragma unroll
    for (int i = 0; i < 4; i++) { ra[i] = f2bits(va[i]); rb[i] = f2bits(vb[i]); }
    ((short4_t*)oa)[idx] = ra;
    ((short4_t*)ob)[idx] = rb;
}

// ---------------------------------------------------------------------------
// prep: transpose + convert the 4 weight matrices [1024][1024] -> bf16 [n][c]
// ---------------------------------------------------------------------------
__global__ void wtrans(const float* __restrict__ w0, const float* __restrict__ w1,
                       const float* __restrict__ w2, const float* __restrict__ w3,
                       short* __restrict__ o0, short* __restrict__ o1,
                       short* __restrict__ o2, short* __restrict__ o3)
{
    __shared__ float tile[64][65];
    const int z = blockIdx.z;
    const float* src = (z == 0) ? w0 : (z == 1) ? w1 : (z == 2) ? w2 : w3;
    short*       dst = (z == 0) ? o0 : (z == 1) ? o1 : (z == 2) ? o2 : o3;
    const int c0 = blockIdx.x * 64, n0 = blockIdx.y * 64;
    const int t = threadIdx.x;
#pragma unroll
    for (int j = 0; j < 16; j++) {
        const int e = t + j * 256;
        tile[e >> 6][e & 63] = src[(long)(c0 + (e >> 6)) * 1024 + n0 + (e & 63)];
    }
    __syncthreads();
#pragma unroll
    for (int j = 0; j < 16; j++) {
        const int e = t + j * 256;
        dst[(long)(n0 + (e >> 6)) * 1024 + c0 + (e & 63)] = f2bits(tile[e & 63][e >> 6]);
    }
}

// ---------------------------------------------------------------------------
// prep: 1-D log-bucket table  ftab[delta+511] = clip(bucket(delta)+256, 0, 511)
// ---------------------------------------------------------------------------
__global__ void ftab_build(int* __restrict__ ftab)
{
    const int i = blockIdx.x * 256 + threadIdx.x;
    if (i >= 1023) return;
    const int delta = i - 511;
    const float Cf = (float)log(511.0 / 128.0);
    float absp = (delta < 128 && delta > -128) ? 127.0f : fabsf((float)delta);
    float bucket;
    if (absp <= 128.0f) {
        bucket = (float)delta;
    } else {
        float lp = ceilf((logf(absp * (1.0f / 128.0f)) * 127.0f) / Cf) + 128.0f;
        bucket = (delta > 0) ? lp : -lp;
    }
    int bi = (int)bucket + 256;
    bi = min(max(bi, 0), 511);
    ftab[i] = bi;
}

// ---------------------------------------------------------------------------
// Generic NT GEMM: C[m,n] = sum_k A[m,k] * BT[n,k]   (bf16 in, fp32 acc)
// tile 128x128, BK=64, 256 threads (4 waves, 2x2), 16x16x32 bf16 MFMA
// Staging via global_load_lds width=16 (linear LDS dest, source pre-swizzled).
// MODE 1: plain -> bf16 out row-major [m*ldo+n], batched by z (O0)
// MODE 2: final -> fp32 out row-major + bias b0 (O0)
// MODE 6: merged projections.
//   z=0 (A=inA,  N=3072): mat0 Q->O0 [b,h,s,d]+b0; mat1 K->O1 +b1;
//                         mat2 V->O2 [b,h,d,s]+b2 (transposed)
//   z=1 (A=A2=inRel, N=2048; y>=16 exits): mat0 posQ->O3 +b0; mat1 posK->O4 +b1
// ---------------------------------------------------------------------------
template<int MODE>
__global__ __launch_bounds__(256)
void gemm_nt(const short* __restrict__ A, long aBatch, int lda,
             const short* __restrict__ BT, long bBatch, int ldb,
             void* __restrict__ O0, void* __restrict__ O1, void* __restrict__ O2,
             long oBatch, int ldo,
             const float* __restrict__ b0, const float* __restrict__ b1,
             const float* __restrict__ b2, int Kd,
             const short* __restrict__ A2,
             void* __restrict__ O3, void* __restrict__ O4)
{
    if (MODE == 6 && blockIdx.z == 1 && blockIdx.y >= 16) return;
    __shared__ __align__(16) short As[128 * 64];
    __shared__ __align__(16) short Bs[128 * 64];
    const int z = blockIdx.z;
    const short* Ab;
    if (MODE == 6 && z == 1) Ab = A2;
    else                     Ab = A + (long)z * aBatch;
    const short* Bb = BT + (long)z * bBatch;
    if (MODE == 6) Bb = BT;   // both z share the concat weight matrix
    const int m0 = blockIdx.x * 128, n0 = blockIdx.y * 128;
    const int t = threadIdx.x;
    const int l = t & 63, w = t >> 6;
    const int wm = w >> 1, wn = w & 1;
    const int lr = l & 15, lg = l >> 4;

    floatx4 acc[4][4];
#pragma unroll
    for (int i = 0; i < 4; i++)
#pragma unroll
        for (int j = 0; j < 4; j++) acc[i][j] = (floatx4){0.f, 0.f, 0.f, 0.f};

    for (int k0 = 0; k0 < Kd; k0 += 64) {
        __syncthreads();
        // async staging: 1024 16B chunks per matrix; LDS linear, source
        // inverse-swizzled (cc = pc ^ (row&7))
#pragma unroll
        for (int j = 0; j < 4; j++) {
            const int c = (w * 4 + j) * 64 + l;   // 0..1023
            const int row = c >> 3, pc = c & 7;
            const int cc = pc ^ (row & 7);
            GLDS16(Ab + (long)(m0 + row) * lda + k0 + cc * 8, As + c * 8);
            GLDS16(Bb + (long)(n0 + row) * ldb + k0 + cc * 8, Bs + c * 8);
        }
        __syncthreads();
#pragma unroll
        for (int ks = 0; ks < 2; ks++) {
            short8 af[4], bfr[4];
#pragma unroll
            for (int i = 0; i < 4; i++) {
                const int mr = wm * 64 + i * 16 + lr;
                af[i] = *(const short8*)((char*)As + mr * 128 + (((ks * 4 + lg) ^ (mr & 7)) * 16));
                const int nr = wn * 64 + i * 16 + lr;
                bfr[i] = *(const short8*)((char*)Bs + nr * 128 + (((ks * 4 + lg) ^ (nr & 7)) * 16));
            }
#pragma unroll
            for (int i = 0; i < 4; i++)
#pragma unroll
                for (int j = 0; j < 4; j++)
                    acc[i][j] = __builtin_amdgcn_mfma_f32_16x16x32_bf16(af[i], bfr[j], acc[i][j], 0, 0, 0);
        }
    }

#pragma unroll
    for (int i = 0; i < 4; i++) {
#pragma unroll
        for (int j = 0; j < 4; j++) {
#pragma unroll
            for (int e = 0; e < 4; e++) {
                const int mg = m0 + wm * 64 + i * 16 + lg * 4 + e;
                const int ng = n0 + wn * 64 + j * 16 + lr;
                float v = acc[i][j][e];
                if (MODE == 1) {
                    ((short*)O0)[(long)z * oBatch + (long)mg * ldo + ng] = f2bits(v);
                } else if (MODE == 2) {
                    ((float*)O0)[(long)mg * ldo + ng] = v + b0[ng];
                } else if (MODE == 6) {
                    const int mat = ng >> 10, hh = ng & 1023, h = hh >> 6, d = hh & 63;
                    const int b = mg >> 9, s = mg & 511;
                    v += (mat == 0 ? b0 : mat == 1 ? b1 : b2)[hh];
                    if (z == 0) {
                        short* dst = (short*)(mat == 0 ? O0 : mat == 1 ? O1 : O2);
                        if (mat == 2)
                            dst[((long)(b * NUM_HEADS + h) * HEAD_DIM + d) * SEQ + s] = f2bits(v);
                        else
                            dst[((long)(b * NUM_HEADS + h) * SEQ + s) * HEAD_DIM + d] = f2bits(v);
                    } else {
                        short* dst = (short*)(mat == 0 ? O3 : O4);
                        dst[((long)(b * NUM_HEADS + h) * SEQ + s) * HEAD_DIM + d] = f2bits(v);
                    }
                }
            }
        }
    }
}

// ---------------------------------------------------------------------------
// p2c_fused: per (k-octant of 64, bh) block (512 threads, 8 waves):
//   strip[p][kk] = sum_d posQ[p][d] * K[k0+kk][d]   (512 x 64, MFMA,
//     bit-identical k-slice accumulation order to the old score GEMM)
//   then G[q][k0+kk] = strip[f(q-k0-kk)][kk]  (gather via LDS, f2bits once)
// Replaces the p2c half of the score GEMM AND the relgather pass (saves
// 134 MB of intermediate traffic). LDS: As 64KB (posQ, then strip) +
// Bs 8KB + ft 2KB = 74KB -> 2 blocks/CU.
// Strip store swizzle: col ^ (((p>>2)&3)<<4) spreads the 4 lg-groups across
// banks; gather reads recompute the same swizzle from fk.
// ---------------------------------------------------------------------------
__global__ __launch_bounds__(512, 2)
void p2c_fused(const short* __restrict__ posQ, const short* __restrict__ K,
               const int* __restrict__ ftab, short* __restrict__ G)
{
    __shared__ __align__(16) short As[512 * 64];   // posQ staged; later strip
    __shared__ __align__(16) short Bs[64 * 64];    // K slice
    __shared__ short ft[1024];
    const int ko = blockIdx.x, bh = blockIdx.y;
    const int k0 = ko * 64;
    const int t = threadIdx.x, l = t & 63, w = t >> 6;
    const int lr = l & 15, lg = l >> 4;
    const short* Ab = posQ + (long)bh * SEQ * HEAD_DIM;
    const short* Kb = K + (long)bh * SEQ * HEAD_DIM;

    for (int i = t; i < 1024; i += 512) ft[i] = (short)((i < 1023) ? ftab[i] : 0);

    // stage posQ: 4096 16B chunks (8/thread), source inverse-swizzled
#pragma unroll
    for (int j = 0; j < 8; j++) {
        const int c = j * 512 + t;            // 0..4095
        const int row = c >> 3, pc = c & 7;
        const int cc = pc ^ (row & 7);
        GLDS16(Ab + (long)row * HEAD_DIM + cc * 8, As + c * 8);
    }
    // stage K slice: 512 chunks (1/thread)
    {
        const int c = t;                      // 0..511
        const int row = c >> 3, pc = c & 7;
        const int cc = pc ^ (row & 7);
        GLDS16(Kb + (long)(k0 + row) * HEAD_DIM + cc * 8, Bs + c * 8);
    }
    __syncthreads();

    // compute strip: wave w owns p-rows [w*64, w*64+64)
    floatx4 acc[4][4];
#pragma unroll
    for (int i = 0; i < 4; i++)
#pragma unroll
        for (int j = 0; j < 4; j++) acc[i][j] = (floatx4){0.f, 0.f, 0.f, 0.f};
#pragma unroll
    for (int ks = 0; ks < 2; ks++) {
        short8 af[4], bfr[4];
#pragma unroll
        for (int i = 0; i < 4; i++) {
            const int mr = w * 64 + i * 16 + lr;
            af[i] = *(const short8*)((char*)As + mr * 128 + (((ks * 4 + lg) ^ (mr & 7)) * 16));
            const int nr = i * 16 + lr;
            bfr[i] = *(const short8*)((char*)Bs + nr * 128 + (((ks * 4 + lg) ^ (nr & 7)) * 16));
        }
#pragma unroll
        for (int i = 0; i < 4; i++)
#pragma unroll
            for (int j = 0; j < 4; j++)
                acc[i][j] = __builtin_amdgcn_mfma_f32_16x16x32_bf16(af[i], bfr[j], acc[i][j], 0, 0, 0);
    }
    __syncthreads();   // all As/Bs reads done -> reuse As as strip

    // store strip (bf16, swizzled col): p = w*64+i*16+lg*4+e, kk = j*16+lr
#pragma unroll
    for (int i = 0; i < 4; i++)
#pragma unroll
        for (int j = 0; j < 4; j++)
#pragma unroll
            for (int e = 0; e < 4; e++) {
                const int p = w * 64 + i * 16 + lg * 4 + e;
                const int kk = j * 16 + lr;
                As[p * 64 + (kk ^ (lg << 4))] = f2bits(acc[i][j][e]);
            }
    __syncthreads();

    // gather + write G: 4096 chunk-tasks (q, kc of 8), 8/thread
    short* Gb = G + (long)bh * SEQ * SEQ;
#pragma unroll
    for (int j = 0; j < 8; j++) {
        const int task = j * 512 + t;
        const int q = task >> 3, kc = task & 7;
        short8 v;
#pragma unroll
        for (int i = 0; i < 8; i++) {
            const int kl = kc * 8 + i;
            const int fk = (int)ft[q - (k0 + kl) + 511];
            v[i] = As[fk * 64 + (kl ^ (((fk >> 2) & 3) << 4))];
        }
        *(short8*)(Gb + (long)q * SEQ + k0 + kc * 8) = v;
    }
}

// ---------------------------------------------------------------------------
// Fused attention per (b,h, 32-row q-tile). 4 waves, 3 barriers. (round-9)
// ---------------------------------------------------------------------------
__global__ __launch_bounds__(256, 4)
void attn_fused(const short* __restrict__ Q, const short* __restrict__ K,
                const short* __restrict__ Vt,
                const short* __restrict__ c2pf, const short* __restrict__ Gp2c,
                const int* __restrict__ ftab,
                short* __restrict__ attnO)
{
    __shared__ __align__(16) short c2pS[32 * 512];  // phase 1: c2p (swz); phase 2: P tile
    __shared__ float red[2][4][32];
    __shared__ short ft[1024];

    const int lin  = blockIdx.x;
    const int lin2 = (lin & 7) * 256 + (lin >> 3);
    const int bh = lin2 >> 4, qt = lin2 & 15;
    const int q0 = qt * 32;
    const int t = threadIdx.x, l = t & 63, w = t >> 6;
    const int lr = l & 15, lg = l >> 4;
    const long pbase = (long)bh * SEQ * HEAD_DIM;
    const short* Qb  = Q  + pbase;
    const short* Kb  = K  + pbase;
    const short* Vtb = Vt + pbase;
    const short* c2pb = c2pf + (long)bh * SEQ * POSN;
    const short* Gb   = Gp2c + (long)bh * SEQ * SEQ;

    for (int i = t; i < 1024; i += 256) ft[i] = (short)((i < 1023) ? ftab[i] : 0);

    // stage 32 c2p rows async, source chunk-swizzled (dest linear)
#pragma unroll
    for (int j = 0; j < 8; j++) {
        const int c = w * 512 + j * 64 + l;   // 0..2047
        const int row = c >> 6, cc = c & 63;
        GLDS16(c2pb + (long)(q0 + row) * POSN + (cc ^ (row & 7)) * 8, c2pS + c * 8);
    }

    short8 aq[2][2];
#pragma unroll
    for (int mt = 0; mt < 2; mt++)
#pragma unroll
        for (int ks = 0; ks < 2; ks++)
            aq[mt][ks] = *(const short8*)(Qb + (q0 + mt * 16 + lr) * 64 + ks * 32 + lg * 8);

    floatx4 acc[2][8];
#pragma unroll
    for (int mt = 0; mt < 2; mt++)
#pragma unroll
        for (int nt = 0; nt < 8; nt++) acc[mt][nt] = (floatx4){0.f, 0.f, 0.f, 0.f};

#pragma unroll
    for (int nt = 0; nt < 8; nt++) {
        const int kr = w * 128 + nt * 16 + lr;
        short8 kb0 = *(const short8*)(Kb + kr * 64 + lg * 8);
        short8 kb1 = *(const short8*)(Kb + kr * 64 + 32 + lg * 8);
#pragma unroll
        for (int mt = 0; mt < 2; mt++) {
            acc[mt][nt] = __builtin_amdgcn_mfma_f32_16x16x32_bf16(aq[mt][0], kb0, acc[mt][nt], 0, 0, 0);
            acc[mt][nt] = __builtin_amdgcn_mfma_f32_16x16x32_bf16(aq[mt][1], kb1, acc[mt][nt], 0, 0, 0);
        }
    }

    __syncthreads();   // staging (vmcnt) + ft visible

#pragma unroll
    for (int mt = 0; mt < 2; mt++)
#pragma unroll
        for (int nt = 0; nt < 8; nt++) {
            const int k = w * 128 + nt * 16 + lr;
#pragma unroll
            for (int e = 0; e < 4; e++) {
                const int r = mt * 16 + lg * 4 + e;
                const int fk = (int)ft[q0 + r - k + 511];
                acc[mt][nt][e] = (acc[mt][nt][e]
                                  + bits2f(c2pS[r * 512 + (fk ^ ((r & 7) << 3))])
                                  + bits2f(Gb[(long)(q0 + r) * SEQ + k])) * SCALE_F;
            }
        }

#pragma unroll
    for (int mt = 0; mt < 2; mt++)
#pragma unroll
        for (int e = 0; e < 4; e++) {
            float m = acc[mt][0][e];
#pragma unroll
            for (int nt = 1; nt < 8; nt++) m = fmaxf(m, acc[mt][nt][e]);
            m = fmaxf(m, __shfl_xor(m, 1));
            m = fmaxf(m, __shfl_xor(m, 2));
            m = fmaxf(m, __shfl_xor(m, 4));
            m = fmaxf(m, __shfl_xor(m, 8));
            red[0][w][mt * 16 + lg * 4 + e] = m;
        }
    __syncthreads();

#pragma unroll
    for (int mt = 0; mt < 2; mt++)
#pragma unroll
        for (int e = 0; e < 4; e++) {
            const int r = mt * 16 + lg * 4 + e;
            const float m = fmaxf(fmaxf(red[0][0][r], red[0][1][r]),
                                  fmaxf(red[0][2][r], red[0][3][r]));
            float s = 0.f;
#pragma unroll
            for (int nt = 0; nt < 8; nt++) {
                float p = __expf(acc[mt][nt][e] - m);
                acc[mt][nt][e] = p;
                s += p;
            }
            s += __shfl_xor(s, 1); s += __shfl_xor(s, 2);
            s += __shfl_xor(s, 4); s += __shfl_xor(s, 8);
            red[1][w][r] = s;
#pragma unroll
            for (int nt = 0; nt < 8; nt++) {
                const int kcol = w * 128 + nt * 16 + lr;
                int byte = r * 1024 + kcol * 2;
                byte ^= (r & 7) << 4;
                *(short*)((char*)c2pS + byte) = f2bits(acc[mt][nt][e]);
            }
        }
    __syncthreads();

    floatx4 accO[2];
    accO[0] = (floatx4){0.f, 0.f, 0.f, 0.f};
    accO[1] = (floatx4){0.f, 0.f, 0.f, 0.f};
#pragma unroll
    for (int ks = 0; ks < 16; ks++) {
        short8 vb = *(const short8*)(Vtb + (long)(w * 16 + lr) * SEQ + ks * 32 + lg * 8);
#pragma unroll
        for (int mt = 0; mt < 2; mt++) {
            const int qr = mt * 16 + lr;
            int byte = qr * 1024 + (ks * 32 + lg * 8) * 2;
            byte ^= (qr & 7) << 4;
            short8 pa = *(const short8*)((char*)c2pS + byte);
            accO[mt] = __builtin_amdgcn_mfma_f32_16x16x32_bf16(pa, vb, accO[mt], 0, 0, 0);
        }
    }

    const int b = bh >> 4, h = bh & 15;
#pragma unroll
    for (int mt = 0; mt < 2; mt++)
#pragma unroll
        for (int e = 0; e < 4; e++) {
            const int r = mt * 16 + lg * 4 + e;
            const float rs = red[1][0][r] + red[1][1][r] + red[1][2][r] + red[1][3][r];
            const float v = accO[mt][e] / rs;
            attnO[((long)(b * SEQ + q0 + r)) * HIDDEN + h * HEAD_DIM + w * 16 + lr] = f2bits(v);
        }
}

// ---------------------------------------------------------------------------
extern "C" void kernel_launch(void* const* d_in, const int* in_sizes, int n_in,
                              void* d_out, int out_size, void* d_ws, size_t ws_size,
                              hipStream_t stream)
{
    const float* inputs = (const float*)d_in[0];
    const float* rel    = (const float*)d_in[1];
    const float* Wq     = (const float*)d_in[2];
    const float* bq     = (const float*)d_in[3];
    const float* Wk     = (const float*)d_in[4];
    const float* bk     = (const float*)d_in[5];
    const float* Wv     = (const float*)d_in[6];
    const float* bv     = (const float*)d_in[7];
    const float* Wo     = (const float*)d_in[8];
    const float* bo     = (const float*)d_in[9];
    float* out = (float*)d_out;

    char* ws = (char*)d_ws;
    size_t off = 0;
    auto alloc = [&](size_t bytes) -> char* {
        char* p = ws + off;
        off += (bytes + 255) & ~(size_t)255;
        return p;
    };
    short* inA   = (short*)alloc(4194304ull * 2);
    short* inRel = (short*)alloc(4194304ull * 2);
    short* WqT   = (short*)alloc(1048576ull * 2);   // WqT/WkT/WvT contiguous ->
    short* WkT   = (short*)alloc(1048576ull * 2);   // concat B for fused GEMMs
    short* WvT   = (short*)alloc(1048576ull * 2);
    short* WoT   = (short*)alloc(1048576ull * 2);
    short* Qw    = (short*)alloc(4194304ull * 2);
    short* Kw    = (short*)alloc(4194304ull * 2);
    short* Vtw   = (short*)alloc(4194304ull * 2);
    short* posQw = (short*)alloc(4194304ull * 2);
    short* posKw = (short*)alloc(4194304ull * 2);
    short* c2pW  = (short*)alloc(33554432ull * 2);
    short* GW    = (short*)alloc(33554432ull * 2);  // p2c pre-gathered (G)
    short* attnW = (short*)alloc(4194304ull * 2);
    int*   ftabW = (int*)alloc(4096);
    // total ws: ~209.7 MB (known-safe footprint)

    // prep
    conv_pair<<<4096, 256, 0, stream>>>(inputs, rel, inA, inRel);
    wtrans<<<dim3(16, 16, 4), 256, 0, stream>>>(Wq, Wk, Wv, Wo, WqT, WkT, WvT, WoT);
    ftab_build<<<4, 256, 0, stream>>>(ftabW);

    // merged projections: z=0 QKV (N=3072), z=1 posQ/posK (N=2048)
    gemm_nt<6><<<dim3(32, 24, 2), 256, 0, stream>>>(inA, 0, 1024, WqT, 0, 1024,
                                                    Qw, Kw, Vtw, 0, 0, bq, bk, bv, 1024,
                                                    inRel, posQw, posKw);

    // c2p score GEMM: c2p = Q @ posK^T  (batched over bh)
    gemm_nt<1><<<dim3(4, 4, 128), 256, 0, stream>>>(Qw, 32768, 64, posKw, 32768, 64,
                                                    c2pW, nullptr, nullptr, 262144, 512,
                                                    nullptr, nullptr, nullptr, 64,
                                                    nullptr, nullptr, nullptr);

    // p2c strip GEMM + gather fused: G[q][k] = (posQ @ K^T)[f(q-k)][k]
    p2c_fused<<<dim3(8, 128), 512, 0, stream>>>(posQw, Kw, ftabW, GW);

    // fused scores+gather+softmax+PV (q-tile 32, 4 blocks/CU)
    attn_fused<<<2048, 256, 0, stream>>>(Qw, Kw, Vtw, c2pW, GW, ftabW, attnW);

    // output projection (fp32 out + bias)
    gemm_nt<2><<<dim3(32, 8), 256, 0, stream>>>(attnW, 0, 1024, WoT, 0, 1024,
                                                out, nullptr, nullptr, 0, 1024, bo, nullptr, nullptr, 1024,
                                                nullptr, nullptr, nullptr);
}

// Round 12
// 204.631 us; speedup vs baseline: 1.3096x; 1.0668x over previous
//
#include <hip/hip_runtime.h>

#define NUM_HEADS 16
#define HEAD_DIM  64
#define HIDDEN    1024
#define SEQ       512
#define BATCH     8
#define NBH       128      // BATCH*NUM_HEADS
#define POSN      512      // 2*BUCKET
#define SCALE_F   0.07216878364870323f   // 1/sqrt(3*HEAD_DIM)

typedef __attribute__((ext_vector_type(8))) short  short8;
typedef __attribute__((ext_vector_type(4))) short  short4_t;
typedef __attribute__((ext_vector_type(4))) float  floatx4;

// async global->LDS, 16B per lane (wave-uniform base + lane*16 dest)
#define GLDS16(gsrc, ldst) \
    __builtin_amdgcn_global_load_lds((const __attribute__((address_space(1))) void*)(gsrc), \
                                     (__attribute__((address_space(3))) void*)(ldst), 16, 0, 0)

__device__ __forceinline__ float bits2f(short s) {
    union { unsigned u; float f; } x;
    x.u = ((unsigned)(unsigned short)s) << 16;
    return x.f;
}
__device__ __forceinline__ short f2bits(float f) {
    union { float f; unsigned u; } x;
    x.f = f;
    unsigned r = x.u + 0x7fffu + ((x.u >> 16) & 1u);
    return (short)(r >> 16);
}

// ---------------------------------------------------------------------------
// prep: fp32 -> bf16 conversion for inputs and rel_embeddings
// ---------------------------------------------------------------------------
__global__ void conv_pair(const float* __restrict__ a, const float* __restrict__ b,
                          short* __restrict__ oa, short* __restrict__ ob)
{
    const int idx = blockIdx.x * 256 + threadIdx.x;    // one float4 each
    floatx4 va = ((const floatx4*)a)[idx];
    floatx4 vb = ((const floatx4*)b)[idx];
    short4_t ra, rb;
#pragma unroll
    for (int i = 0; i < 4; i++) { ra[i] = f2bits(va[i]); rb[i] = f2bits(vb[i]); }
    ((short4_t*)oa)[idx] = ra;
    ((short4_t*)ob)[idx] = rb;
}

// ---------------------------------------------------------------------------
// prep: transpose + convert the 4 weight matrices [1024][1024] -> bf16 [n][c]
// ---------------------------------------------------------------------------
__global__ void wtrans(const float* __restrict__ w0, const float* __restrict__ w1,
                       const float* __restrict__ w2, const float* __restrict__ w3,
                       short* __restrict__ o0, short* __restrict__ o1,
                       short* __restrict__ o2, short* __restrict__ o3)
{
    __shared__ float tile[64][65];
    const int z = blockIdx.z;
    const float* src = (z == 0) ? w0 : (z == 1) ? w1 : (z == 2) ? w2 : w3;
    short*       dst = (z == 0) ? o0 : (z == 1) ? o1 : (z == 2) ? o2 : o3;
    const int c0 = blockIdx.x * 64, n0 = blockIdx.y * 64;
    const int t = threadIdx.x;
#pragma unroll
    for (int j = 0; j < 16; j++) {
        const int e = t + j * 256;
        tile[e >> 6][e & 63] = src[(long)(c0 + (e >> 6)) * 1024 + n0 + (e & 63)];
    }
    __syncthreads();
#pragma unroll
    for (int j = 0; j < 16; j++) {
        const int e = t + j * 256;
        dst[(long)(n0 + (e >> 6)) * 1024 + c0 + (e & 63)] = f2bits(tile[e & 63][e >> 6]);
    }
}

// ---------------------------------------------------------------------------
// prep: 1-D log-bucket table  ftab[delta+511] = clip(bucket(delta)+256, 0, 511)
// ---------------------------------------------------------------------------
__global__ void ftab_build(int* __restrict__ ftab)
{
    const int i = blockIdx.x * 256 + threadIdx.x;
    if (i >= 1023) return;
    const int delta = i - 511;
    const float Cf = (float)log(511.0 / 128.0);
    float absp = (delta < 128 && delta > -128) ? 127.0f : fabsf((float)delta);
    float bucket;
    if (absp <= 128.0f) {
        bucket = (float)delta;
    } else {
        float lp = ceilf((logf(absp * (1.0f / 128.0f)) * 127.0f) / Cf) + 128.0f;
        bucket = (delta > 0) ? lp : -lp;
    }
    int bi = (int)bucket + 256;
    bi = min(max(bi, 0), 511);
    ftab[i] = bi;
}

// ---------------------------------------------------------------------------
// Generic NT GEMM: C[m,n] = sum_k A[m,k] * BT[n,k]   (bf16 in, fp32 acc)
// tile 128x128, BK=64, 256 threads (4 waves, 2x2), 16x16x32 bf16 MFMA.
// 2-phase DOUBLE-BUFFERED pipeline: issue next tile's global_load_lds BEFORE
// computing current tile; single barrier per iter. LDS 64 KB.
// MODE 1: plain -> bf16 out row-major [m*ldo+n], batched by z (O0)
// MODE 2: final -> fp32 out row-major + bias b0 (O0)
// MODE 6: merged projections, grid (32, 40), XCD-chunked swizzle.
//   yy<16:  Q->O0 [b,h,s,d]+b0 / K->O1 +b1 (mat by ng)
//   16<=yy<24: V->O2 [b,h,d,s]+b2, via LDS-transpose epilogue (coalesced)
//   yy>=24: A=A2(inRel), n0=(yy-24)*128: posQ->O3 +b0 / posK->O4 +b1
// ---------------------------------------------------------------------------
template<int MODE>
__global__ __launch_bounds__(256)
void gemm_nt(const short* __restrict__ A, long aBatch, int lda,
             const short* __restrict__ BT, long bBatch, int ldb,
             void* __restrict__ O0, void* __restrict__ O1, void* __restrict__ O2,
             long oBatch, int ldo,
             const float* __restrict__ b0, const float* __restrict__ b1,
             const float* __restrict__ b2, int Kd,
             const short* __restrict__ A2,
             void* __restrict__ O3, void* __restrict__ O4)
{
    __shared__ __align__(16) short As[2][128 * 64];
    __shared__ __align__(16) short Bs[2][128 * 64];

    int m0, n0, yy = 0;
    bool z1 = false;
    const int z = blockIdx.z;
    if (MODE == 6) {
        const int lin = blockIdx.x + (blockIdx.y << 5);      // 0..1279
        const int swz = (lin & 7) * 160 + (lin >> 3);        // XCD-chunked
        m0 = (swz & 31) * 128;
        yy = swz >> 5;                                        // 0..39
        z1 = (yy >= 24);
        n0 = (z1 ? (yy - 24) : yy) * 128;
    } else {
        m0 = blockIdx.x * 128;
        n0 = blockIdx.y * 128;
    }

    const short* Ab;
    const short* Bb;
    if (MODE == 6) {
        Ab = z1 ? A2 : A;
        Bb = BT;
    } else {
        Ab = A + (long)z * aBatch;
        Bb = BT + (long)z * bBatch;
    }

    const int t = threadIdx.x;
    const int l = t & 63, w = t >> 6;
    const int wm = w >> 1, wn = w & 1;
    const int lr = l & 15, lg = l >> 4;

    floatx4 acc[4][4];
#pragma unroll
    for (int i = 0; i < 4; i++)
#pragma unroll
        for (int j = 0; j < 4; j++) acc[i][j] = (floatx4){0.f, 0.f, 0.f, 0.f};

    // prologue: stage tile 0 into buffer 0
#pragma unroll
    for (int j = 0; j < 4; j++) {
        const int c = (w * 4 + j) * 64 + l;   // 0..1023
        const int row = c >> 3, pc = c & 7;
        const int cc = pc ^ (row & 7);
        GLDS16(Ab + (long)(m0 + row) * lda + cc * 8, As[0] + c * 8);
        GLDS16(Bb + (long)(n0 + row) * ldb + cc * 8, Bs[0] + c * 8);
    }
    __syncthreads();   // vmcnt drain + barrier: buffer 0 ready

    int cur = 0;
    for (int k0 = 0; k0 < Kd; k0 += 64, cur ^= 1) {
        // issue next tile's loads into the other buffer (overlaps compute)
        if (k0 + 64 < Kd) {
            const int kn = k0 + 64;
#pragma unroll
            for (int j = 0; j < 4; j++) {
                const int c = (w * 4 + j) * 64 + l;
                const int row = c >> 3, pc = c & 7;
                const int cc = pc ^ (row & 7);
                GLDS16(Ab + (long)(m0 + row) * lda + kn + cc * 8, As[cur ^ 1] + c * 8);
                GLDS16(Bb + (long)(n0 + row) * ldb + kn + cc * 8, Bs[cur ^ 1] + c * 8);
            }
        }
        // compute current buffer
#pragma unroll
        for (int ks = 0; ks < 2; ks++) {
            short8 af[4], bfr[4];
#pragma unroll
            for (int i = 0; i < 4; i++) {
                const int mr = wm * 64 + i * 16 + lr;
                af[i] = *(const short8*)((char*)As[cur] + mr * 128 + (((ks * 4 + lg) ^ (mr & 7)) * 16));
                const int nr = wn * 64 + i * 16 + lr;
                bfr[i] = *(const short8*)((char*)Bs[cur] + nr * 128 + (((ks * 4 + lg) ^ (nr & 7)) * 16));
            }
#pragma unroll
            for (int i = 0; i < 4; i++)
#pragma unroll
                for (int j = 0; j < 4; j++)
                    acc[i][j] = __builtin_amdgcn_mfma_f32_16x16x32_bf16(af[i], bfr[j], acc[i][j], 0, 0, 0);
        }
        __syncthreads();   // all reads of cur done; next buffer's loads drained
    }

    // ---- epilogue ----
    if (MODE == 6 && !z1 && yy >= 16) {
        // V quadrant: transpose via LDS (As[0]+As[1] = 32 KB), coalesced stores
        short* tp = &As[0][0];   // [128 rows ngl][128 cols ml], XOR-swizzled
#pragma unroll
        for (int i = 0; i < 4; i++)
#pragma unroll
            for (int j = 0; j < 4; j++)
#pragma unroll
                for (int e = 0; e < 4; e++) {
                    const int ml  = wm * 64 + i * 16 + lg * 4 + e;   // local m (=s)
                    const int ngl = wn * 64 + j * 16 + lr;           // local n
                    const float v = acc[i][j][e] + b2[(n0 & 1023) + ngl];
                    tp[ngl * 128 + (ml ^ ((ngl & 7) << 4))] = f2bits(v);
                }
        __syncthreads();
        const int b = m0 >> 9, s0 = m0 & 511;
        const int hb = (n0 & 1023) >> 6;
        short* dst = (short*)O2;
        // 2048 tasks: 128 rows x 16 chunks of 8 (FULL 128-wide s coverage)
#pragma unroll
        for (int j = 0; j < 8; j++) {
            const int task = t + j * 256;            // 0..2047
            const int r = task >> 4, c = task & 15;  // row ngl, 16B chunk
            short8 v8 = *(const short8*)(tp + r * 128 + ((c * 8) ^ ((r & 7) << 4)));
            const int h = hb + (r >> 6), d = r & 63;
            *(short8*)(dst + ((long)((b * NUM_HEADS + h) * HEAD_DIM + d)) * SEQ + s0 + c * 8) = v8;
        }
        return;
    }

#pragma unroll
    for (int i = 0; i < 4; i++) {
#pragma unroll
        for (int j = 0; j < 4; j++) {
#pragma unroll
            for (int e = 0; e < 4; e++) {
                const int mg = m0 + wm * 64 + i * 16 + lg * 4 + e;
                const int ng = n0 + wn * 64 + j * 16 + lr;
                float v = acc[i][j][e];
                if (MODE == 1) {
                    ((short*)O0)[(long)z * oBatch + (long)mg * ldo + ng] = f2bits(v);
                } else if (MODE == 2) {
                    ((float*)O0)[(long)mg * ldo + ng] = v + b0[ng];
                } else if (MODE == 6) {
                    const int hh = ng & 1023, mat = ng >> 10;
                    const int h = hh >> 6, d = hh & 63;
                    const int b = mg >> 9, s = mg & 511;
                    v += (mat == 0 ? b0 : b1)[hh];
                    short* dst;
                    if (z1) dst = (short*)(mat == 0 ? O3 : O4);
                    else    dst = (short*)(mat == 0 ? O0 : O1);
                    dst[((long)(b * NUM_HEADS + h) * SEQ + s) * HEAD_DIM + d] = f2bits(v);
                }
            }
        }
    }
}

// ---------------------------------------------------------------------------
// p2c_fused: per (k-octant of 64, bh) block (512 threads, 8 waves):
//   strip[p][kk] = sum_d posQ[p][d] * K[k0+kk][d]   (512 x 64, MFMA)
//   then G[q][k0+kk] = strip[f(q-k0-kk)][kk]  (gather via LDS, f2bits once)
// ---------------------------------------------------------------------------
__global__ __launch_bounds__(512, 2)
void p2c_fused(const short* __restrict__ posQ, const short* __restrict__ K,
               const int* __restrict__ ftab, short* __restrict__ G)
{
    __shared__ __align__(16) short As[512 * 64];   // posQ staged; later strip
    __shared__ __align__(16) short Bs[64 * 64];    // K slice
    __shared__ short ft[1024];
    const int ko = blockIdx.x, bh = blockIdx.y;
    const int k0 = ko * 64;
    const int t = threadIdx.x, l = t & 63, w = t >> 6;
    const int lr = l & 15, lg = l >> 4;
    const short* Ab = posQ + (long)bh * SEQ * HEAD_DIM;
    const short* Kb = K + (long)bh * SEQ * HEAD_DIM;

    for (int i = t; i < 1024; i += 512) ft[i] = (short)((i < 1023) ? ftab[i] : 0);

#pragma unroll
    for (int j = 0; j < 8; j++) {
        const int c = j * 512 + t;            // 0..4095
        const int row = c >> 3, pc = c & 7;
        const int cc = pc ^ (row & 7);
        GLDS16(Ab + (long)row * HEAD_DIM + cc * 8, As + c * 8);
    }
    {
        const int c = t;                      // 0..511
        const int row = c >> 3, pc = c & 7;
        const int cc = pc ^ (row & 7);
        GLDS16(Kb + (long)(k0 + row) * HEAD_DIM + cc * 8, Bs + c * 8);
    }
    __syncthreads();

    floatx4 acc[4][4];
#pragma unroll
    for (int i = 0; i < 4; i++)
#pragma unroll
        for (int j = 0; j < 4; j++) acc[i][j] = (floatx4){0.f, 0.f, 0.f, 0.f};
#pragma unroll
    for (int ks = 0; ks < 2; ks++) {
        short8 af[4], bfr[4];
#pragma unroll
        for (int i = 0; i < 4; i++) {
            const int mr = w * 64 + i * 16 + lr;
            af[i] = *(const short8*)((char*)As + mr * 128 + (((ks * 4 + lg) ^ (mr & 7)) * 16));
            const int nr = i * 16 + lr;
            bfr[i] = *(const short8*)((char*)Bs + nr * 128 + (((ks * 4 + lg) ^ (nr & 7)) * 16));
        }
#pragma unroll
        for (int i = 0; i < 4; i++)
#pragma unroll
            for (int j = 0; j < 4; j++)
                acc[i][j] = __builtin_amdgcn_mfma_f32_16x16x32_bf16(af[i], bfr[j], acc[i][j], 0, 0, 0);
    }
    __syncthreads();   // all As/Bs reads done -> reuse As as strip

#pragma unroll
    for (int i = 0; i < 4; i++)
#pragma unroll
        for (int j = 0; j < 4; j++)
#pragma unroll
            for (int e = 0; e < 4; e++) {
                const int p = w * 64 + i * 16 + lg * 4 + e;
                const int kk = j * 16 + lr;
                As[p * 64 + (kk ^ (lg << 4))] = f2bits(acc[i][j][e]);
            }
    __syncthreads();

    short* Gb = G + (long)bh * SEQ * SEQ;
#pragma unroll
    for (int j = 0; j < 8; j++) {
        const int task = j * 512 + t;
        const int q = task >> 3, kc = task & 7;
        short8 v;
#pragma unroll
        for (int i = 0; i < 8; i++) {
            const int kl = kc * 8 + i;
            const int fk = (int)ft[q - (k0 + kl) + 511];
            v[i] = As[fk * 64 + (kl ^ (((fk >> 2) & 3) << 4))];
        }
        *(short8*)(Gb + (long)q * SEQ + k0 + kc * 8) = v;
    }
}

// ---------------------------------------------------------------------------
// Fused attention per (b,h, 32-row q-tile). 4 waves, 3 barriers. (round-9)
// ---------------------------------------------------------------------------
__global__ __launch_bounds__(256, 4)
void attn_fused(const short* __restrict__ Q, const short* __restrict__ K,
                const short* __restrict__ Vt,
                const short* __restrict__ c2pf, const short* __restrict__ Gp2c,
                const int* __restrict__ ftab,
                short* __restrict__ attnO)
{
    __shared__ __align__(16) short c2pS[32 * 512];  // phase 1: c2p (swz); phase 2: P tile
    __shared__ float red[2][4][32];
    __shared__ short ft[1024];

    const int lin  = blockIdx.x;
    const int lin2 = (lin & 7) * 256 + (lin >> 3);
    const int bh = lin2 >> 4, qt = lin2 & 15;
    const int q0 = qt * 32;
    const int t = threadIdx.x, l = t & 63, w = t >> 6;
    const int lr = l & 15, lg = l >> 4;
    const long pbase = (long)bh * SEQ * HEAD_DIM;
    const short* Qb  = Q  + pbase;
    const short* Kb  = K  + pbase;
    const short* Vtb = Vt + pbase;
    const short* c2pb = c2pf + (long)bh * SEQ * POSN;
    const short* Gb   = Gp2c + (long)bh * SEQ * SEQ;

    for (int i = t; i < 1024; i += 256) ft[i] = (short)((i < 1023) ? ftab[i] : 0);

#pragma unroll
    for (int j = 0; j < 8; j++) {
        const int c = w * 512 + j * 64 + l;   // 0..2047
        const int row = c >> 6, cc = c & 63;
        GLDS16(c2pb + (long)(q0 + row) * POSN + (cc ^ (row & 7)) * 8, c2pS + c * 8);
    }

    short8 aq[2][2];
#pragma unroll
    for (int mt = 0; mt < 2; mt++)
#pragma unroll
        for (int ks = 0; ks < 2; ks++)
            aq[mt][ks] = *(const short8*)(Qb + (q0 + mt * 16 + lr) * 64 + ks * 32 + lg * 8);

    floatx4 acc[2][8];
#pragma unroll
    for (int mt = 0; mt < 2; mt++)
#pragma unroll
        for (int nt = 0; nt < 8; nt++) acc[mt][nt] = (floatx4){0.f, 0.f, 0.f, 0.f};

#pragma unroll
    for (int nt = 0; nt < 8; nt++) {
        const int kr = w * 128 + nt * 16 + lr;
        short8 kb0 = *(const short8*)(Kb + kr * 64 + lg * 8);
        short8 kb1 = *(const short8*)(Kb + kr * 64 + 32 + lg * 8);
#pragma unroll
        for (int mt = 0; mt < 2; mt++) {
            acc[mt][nt] = __builtin_amdgcn_mfma_f32_16x16x32_bf16(aq[mt][0], kb0, acc[mt][nt], 0, 0, 0);
            acc[mt][nt] = __builtin_amdgcn_mfma_f32_16x16x32_bf16(aq[mt][1], kb1, acc[mt][nt], 0, 0, 0);
        }
    }

    __syncthreads();   // staging (vmcnt) + ft visible

#pragma unroll
    for (int mt = 0; mt < 2; mt++)
#pragma unroll
        for (int nt = 0; nt < 8; nt++) {
            const int k = w * 128 + nt * 16 + lr;
#pragma unroll
            for (int e = 0; e < 4; e++) {
                const int r = mt * 16 + lg * 4 + e;
                const int fk = (int)ft[q0 + r - k + 511];
                acc[mt][nt][e] = (acc[mt][nt][e]
                                  + bits2f(c2pS[r * 512 + (fk ^ ((r & 7) << 3))])
                                  + bits2f(Gb[(long)(q0 + r) * SEQ + k])) * SCALE_F;
            }
        }

#pragma unroll
    for (int mt = 0; mt < 2; mt++)
#pragma unroll
        for (int e = 0; e < 4; e++) {
            float m = acc[mt][0][e];
#pragma unroll
            for (int nt = 1; nt < 8; nt++) m = fmaxf(m, acc[mt][nt][e]);
            m = fmaxf(m, __shfl_xor(m, 1));
            m = fmaxf(m, __shfl_xor(m, 2));
            m = fmaxf(m, __shfl_xor(m, 4));
            m = fmaxf(m, __shfl_xor(m, 8));
            red[0][w][mt * 16 + lg * 4 + e] = m;
        }
    __syncthreads();

#pragma unroll
    for (int mt = 0; mt < 2; mt++)
#pragma unroll
        for (int e = 0; e < 4; e++) {
            const int r = mt * 16 + lg * 4 + e;
            const float m = fmaxf(fmaxf(red[0][0][r], red[0][1][r]),
                                  fmaxf(red[0][2][r], red[0][3][r]));
            float s = 0.f;
#pragma unroll
            for (int nt = 0; nt < 8; nt++) {
                float p = __expf(acc[mt][nt][e] - m);
                acc[mt][nt][e] = p;
                s += p;
            }
            s += __shfl_xor(s, 1); s += __shfl_xor(s, 2);
            s += __shfl_xor(s, 4); s += __shfl_xor(s, 8);
            red[1][w][r] = s;
#pragma unroll
            for (int nt = 0; nt < 8; nt++) {
                const int kcol = w * 128 + nt * 16 + lr;
                int byte = r * 1024 + kcol * 2;
                byte ^= (r & 7) << 4;
                *(short*)((char*)c2pS + byte) = f2bits(acc[mt][nt][e]);
            }
        }
    __syncthreads();

    floatx4 accO[2];
    accO[0] = (floatx4){0.f, 0.f, 0.f, 0.f};
    accO[1] = (floatx4){0.f, 0.f, 0.f, 0.f};
#pragma unroll
    for (int ks = 0; ks < 16; ks++) {
        short8 vb = *(const short8*)(Vtb + (long)(w * 16 + lr) * SEQ + ks * 32 + lg * 8);
#pragma unroll
        for (int mt = 0; mt < 2; mt++) {
            const int qr = mt * 16 + lr;
            int byte = qr * 1024 + (ks * 32 + lg * 8) * 2;
            byte ^= (qr & 7) << 4;
            short8 pa = *(const short8*)((char*)c2pS + byte);
            accO[mt] = __builtin_amdgcn_mfma_f32_16x16x32_bf16(pa, vb, accO[mt], 0, 0, 0);
        }
    }

    const int b = bh >> 4, h = bh & 15;
#pragma unroll
    for (int mt = 0; mt < 2; mt++)
#pragma unroll
        for (int e = 0; e < 4; e++) {
            const int r = mt * 16 + lg * 4 + e;
            const float rs = red[1][0][r] + red[1][1][r] + red[1][2][r] + red[1][3][r];
            const float v = accO[mt][e] / rs;
            attnO[((long)(b * SEQ + q0 + r)) * HIDDEN + h * HEAD_DIM + w * 16 + lr] = f2bits(v);
        }
}

// ---------------------------------------------------------------------------
extern "C" void kernel_launch(void* const* d_in, const int* in_sizes, int n_in,
                              void* d_out, int out_size, void* d_ws, size_t ws_size,
                              hipStream_t stream)
{
    const float* inputs = (const float*)d_in[0];
    const float* rel    = (const float*)d_in[1];
    const float* Wq     = (const float*)d_in[2];
    const float* bq     = (const float*)d_in[3];
    const float* Wk     = (const float*)d_in[4];
    const float* bk     = (const float*)d_in[5];
    const float* Wv     = (const float*)d_in[6];
    const float* bv     = (const float*)d_in[7];
    const float* Wo     = (const float*)d_in[8];
    const float* bo     = (const float*)d_in[9];
    float* out = (float*)d_out;

    char* ws = (char*)d_ws;
    size_t off = 0;
    auto alloc = [&](size_t bytes) -> char* {
        char* p = ws + off;
        off += (bytes + 255) & ~(size_t)255;
        return p;
    };
    short* inA   = (short*)alloc(4194304ull * 2);
    short* inRel = (short*)alloc(4194304ull * 2);
    short* WqT   = (short*)alloc(1048576ull * 2);   // WqT/WkT/WvT contiguous ->
    short* WkT   = (short*)alloc(1048576ull * 2);   // concat B for fused GEMMs
    short* WvT   = (short*)alloc(1048576ull * 2);
    short* WoT   = (short*)alloc(1048576ull * 2);
    short* Qw    = (short*)alloc(4194304ull * 2);
    short* Kw    = (short*)alloc(4194304ull * 2);
    short* Vtw   = (short*)alloc(4194304ull * 2);
    short* posQw = (short*)alloc(4194304ull * 2);
    short* posKw = (short*)alloc(4194304ull * 2);
    short* c2pW  = (short*)alloc(33554432ull * 2);
    short* GW    = (short*)alloc(33554432ull * 2);  // p2c pre-gathered (G)
    short* attnW = (short*)alloc(4194304ull * 2);
    int*   ftabW = (int*)alloc(4096);
    // total ws: ~209.7 MB (known-safe footprint)

    // prep
    conv_pair<<<4096, 256, 0, stream>>>(inputs, rel, inA, inRel);
    wtrans<<<dim3(16, 16, 4), 256, 0, stream>>>(Wq, Wk, Wv, Wo, WqT, WkT, WvT, WoT);
    ftab_build<<<4, 256, 0, stream>>>(ftabW);

    // merged projections: QKV (yy<24) + posQ/posK (yy>=24), dense grid
    gemm_nt<6><<<dim3(32, 40), 256, 0, stream>>>(inA, 0, 1024, WqT, 0, 1024,
                                                 Qw, Kw, Vtw, 0, 0, bq, bk, bv, 1024,
                                                 inRel, posQw, posKw);

    // c2p score GEMM: c2p = Q @ posK^T  (batched over bh)
    gemm_nt<1><<<dim3(4, 4, 128), 256, 0, stream>>>(Qw, 32768, 64, posKw, 32768, 64,
                                                    c2pW, nullptr, nullptr, 262144, 512,
                                                    nullptr, nullptr, nullptr, 64,
                                                    nullptr, nullptr, nullptr);

    // p2c strip GEMM + gather fused: G[q][k] = (posQ @ K^T)[f(q-k)][k]
    p2c_fused<<<dim3(8, 128), 512, 0, stream>>>(posQw, Kw, ftabW, GW);

    // fused scores+gather+softmax+PV (q-tile 32, 4 blocks/CU)
    attn_fused<<<2048, 256, 0, stream>>>(Qw, Kw, Vtw, c2pW, GW, ftabW, attnW);

    // output projection (fp32 out + bias)
    gemm_nt<2><<<dim3(32, 8), 256, 0, stream>>>(attnW, 0, 1024, WoT, 0, 1024,
                                                out, nullptr, nullptr, 0, 1024, bo, nullptr, nullptr, 1024,
                                                nullptr, nullptr, nullptr);
}